// Round 1
// baseline (1975.096 us; speedup 1.0000x reference)
//
#include <hip/hip_runtime.h>
#include <math.h>

// Problem constants: B=8, H=W=56, C=512, N=3136, c4=128, HEADS=8, hd=64, SR=2
// kv sequence length = 14*14 = 196

// ---------------- workspace layout (float offsets) ----------------
// q_buf : 25088*512          = 12,845,056
// cat   : 25088*640          = 16,056,320   (cols 0..511 = attn o, 512..639 = idwt)
// r     : 8*3136*128         =  3,211,264   (NHWC, fp16-rounded)  [aliased later by dwt_b]
// dwt_a : 8*784*512          =  3,211,264   (NHWC)                [aliased later by kv_in]
// kv    : 8*196*1024         =  1,605,632
// wT    : 512*4608           =  2,359,296
// kveT  : 512*2048           =  1,048,576
static const size_t OFF_Q    = 0;
static const size_t OFF_CAT  = 12845056;
static const size_t OFF_R    = 28901376;
static const size_t OFF_DWTA = 32112640;
static const size_t OFF_KV   = 35323904;
static const size_t OFF_WT   = 36929536;
static const size_t OFF_KVET = 39288832;
// total = 40,337,408 floats = 153.9 MB

// BN scale constant: 1/sqrt(1 + 1e-5)
#define BN_RSQ 0.9999950000374997f

// =====================================================================
// Generic NT GEMM: out[m][n] = sum_k A[m][k] * W[n][k]  (+ epilogue)
// ALOAD: 0 = plain row-major A (lda), 1 = conv3x3 implicit (NHWC 28x28, pad 1),
//        2 = kve 2x2 stride-2 implicit (NHWC 28x28 -> 14x14)
// EPI:   0 = +bias,   1 = +bias, BN(g,beta), ReLU, fp16-round
// Tile 64x64, BK=16, 256 threads, 4x4 per thread.
// =====================================================================
template <int ALOAD, int EPI>
__global__ __launch_bounds__(256) void gemm_nt(
    const float* __restrict__ A, const float* __restrict__ W,
    float* __restrict__ Cd, int M, int K, int lda, int ldw, int ldc,
    const float* __restrict__ bias, const float* __restrict__ bng,
    const float* __restrict__ bnb)
{
    __shared__ float As[16][68];
    __shared__ float Bs[16][68];
    const int t  = threadIdx.x;
    const int tx = t & 15, ty = t >> 4;
    const int m0 = blockIdx.x * 64, n0 = blockIdx.y * 64;
    const int lr = t >> 2;          // 0..63: tile row loaded by this thread
    const int lk = (t & 3) * 4;     // 0,4,8,12: k offset within chunk

    const int aRow = m0 + lr;
    bool rowValid = true;
    int bb = 0, yy = 0, xx = 0;
    if constexpr (ALOAD == 0) {
        rowValid = (aRow < M);
    } else if constexpr (ALOAD == 1) {  // m = b*784 + y*28 + x
        bb = aRow / 784; int rem = aRow - bb * 784;
        yy = rem / 28;   xx = rem - yy * 28;
    } else {                             // m = b*196 + i*14 + j
        rowValid = (aRow < M);
        int ar = rowValid ? aRow : 0;
        bb = ar / 196; int rem = ar - bb * 196;
        yy = rem / 14; xx = rem - yy * 14;
    }

    float acc[4][4];
#pragma unroll
    for (int i = 0; i < 4; ++i)
#pragma unroll
        for (int j = 0; j < 4; ++j) acc[i][j] = 0.0f;

    for (int k0 = 0; k0 < K; k0 += 16) {
        float4 av = make_float4(0.f, 0.f, 0.f, 0.f);
        float4 bv;
        if constexpr (ALOAD == 0) {
            if (rowValid)
                av = *(const float4*)(A + (size_t)aRow * lda + k0 + lk);
        } else if constexpr (ALOAD == 1) {
            int sub = k0 >> 9;            // (ky*3+kx), uniform per chunk
            int s3  = sub / 3;
            int dy  = s3 - 1, dx = (sub - s3 * 3) - 1;
            int y2 = yy + dy, x2 = xx + dx;
            if ((unsigned)y2 < 28u && (unsigned)x2 < 28u)
                av = *(const float4*)(A + ((size_t)(bb * 784 + y2 * 28 + x2)) * 512
                                        + (k0 & 511) + lk);
        } else {
            int sub = k0 >> 9;            // (ky*2+kx)
            int ky = sub >> 1, kx = sub & 1;
            int y2 = 2 * yy + ky, x2 = 2 * xx + kx;
            if (rowValid)
                av = *(const float4*)(A + ((size_t)(bb * 784 + y2 * 28 + x2)) * 512
                                        + (k0 & 511) + lk);
        }
        bv = *(const float4*)(W + (size_t)(n0 + lr) * ldw + k0 + lk);

        __syncthreads();   // previous iteration's compute done reading LDS
        As[lk + 0][lr] = av.x; As[lk + 1][lr] = av.y;
        As[lk + 2][lr] = av.z; As[lk + 3][lr] = av.w;
        Bs[lk + 0][lr] = bv.x; Bs[lk + 1][lr] = bv.y;
        Bs[lk + 2][lr] = bv.z; Bs[lk + 3][lr] = bv.w;
        __syncthreads();

#pragma unroll
        for (int kk = 0; kk < 16; ++kk) {
            float a[4], b[4];
            *(float4*)a = *(const float4*)&As[kk][ty * 4];
            *(float4*)b = *(const float4*)&Bs[kk][tx * 4];
#pragma unroll
            for (int i = 0; i < 4; ++i)
#pragma unroll
                for (int j = 0; j < 4; ++j) acc[i][j] += a[i] * b[j];
        }
    }

#pragma unroll
    for (int i = 0; i < 4; ++i) {
        int m = m0 + ty * 4 + i;
        if (m >= M) continue;
#pragma unroll
        for (int j = 0; j < 4; ++j) {
            int n = n0 + tx * 4 + j;
            float v = acc[i][j] + bias[n];
            if constexpr (EPI == 1) {
                v = v * (bng[n] * BN_RSQ) + bnb[n];
                v = fmaxf(v, 0.0f);
                v = (float)(_Float16)v;   // replicate .astype(fp16)
            }
            Cd[(size_t)m * ldc + n] = v;
        }
    }
}

// =====================================================================
// Weight transposes
// =====================================================================
__global__ __launch_bounds__(256) void transpose_filter(
    const float* __restrict__ fw, float* __restrict__ wT)
{   // wT[n][(ky*3+kx)*512 + ci] = fw[n][ci][ky][kx];  512*4608 elements
    int idx = blockIdx.x * 256 + threadIdx.x;
    int n = idx / 4608; int r = idx - n * 4608;
    int sub = r >> 9; int ci = r & 511;
    wT[idx] = fw[(size_t)n * 4608 + ci * 9 + sub];
}

__global__ __launch_bounds__(256) void transpose_kve(
    const float* __restrict__ kw, float* __restrict__ kT)
{   // kT[n][(ky*2+kx)*512 + ci] = kw[n][ci][ky][kx];  512*2048 elements
    int idx = blockIdx.x * 256 + threadIdx.x;
    int n = idx >> 11; int r = idx & 2047;
    int sub = r >> 9; int ci = r & 511;
    kT[idx] = kw[((size_t)n << 11) + (ci << 2) + sub];
}

// =====================================================================
// Haar DWT: r (B,56,56,128 NHWC, fp16-valued) -> dwt_a (B,28,28,512 NHWC)
// fp16 arithmetic, reference order: ((x1 op x2) op x3) op x4
// =====================================================================
__global__ __launch_bounds__(128) void dwt_kernel(
    const float* __restrict__ r, float* __restrict__ dwt)
{
    int bid = blockIdx.x;            // b*784 + i*28 + j
    int b = bid / 784; int rem = bid - b * 784;
    int i = rem / 28;  int j = rem - i * 28;
    int c = threadIdx.x;
    int y = 2 * i, x = 2 * j;
    size_t base = (size_t)b * 3136;
    float f1 = r[(base + (size_t)y * 56 + x) * 128 + c];           // (0::2,0::2)
    float f2 = r[(base + (size_t)(y + 1) * 56 + x) * 128 + c];     // (1::2,0::2)
    float f3 = r[(base + (size_t)y * 56 + (x + 1)) * 128 + c];     // (0::2,1::2)
    float f4 = r[(base + (size_t)(y + 1) * 56 + (x + 1)) * 128 + c];
    _Float16 h = (_Float16)0.5f;
    _Float16 x1 = (_Float16)f1 * h, x2 = (_Float16)f2 * h;
    _Float16 x3 = (_Float16)f3 * h, x4 = (_Float16)f4 * h;
    _Float16 ll = ((x1 + x2) + x3) + x4;
    _Float16 hl = (((-x1) - x2) + x3) + x4;
    _Float16 lh = (((-x1) + x2) - x3) + x4;
    _Float16 hh = ((x1 - x2) - x3) + x4;
    size_t ob = ((size_t)b * 784 + (size_t)i * 28 + j) * 512;
    dwt[ob + c]       = (float)ll;
    dwt[ob + 128 + c] = (float)hl;
    dwt[ob + 256 + c] = (float)lh;
    dwt[ob + 384 + c] = (float)hh;
}

// =====================================================================
// Haar IDWT: dwt_b (B,28,28,512 NHWC fp16-valued) -> cat cols 512..639
// =====================================================================
__global__ __launch_bounds__(128) void idwt_kernel(
    const float* __restrict__ d, float* __restrict__ cat)
{
    int bid = blockIdx.x;
    int b = bid / 784; int rem = bid - b * 784;
    int i = rem / 28;  int j = rem - i * 28;
    int c = threadIdx.x;
    size_t ib = ((size_t)b * 784 + (size_t)i * 28 + j) * 512;
    _Float16 ll = (_Float16)d[ib + c];
    _Float16 hl = (_Float16)d[ib + 128 + c];
    _Float16 lh = (_Float16)d[ib + 256 + c];
    _Float16 hh = (_Float16)d[ib + 384 + c];
    _Float16 h = (_Float16)0.5f;
    _Float16 p1 = (((ll - hl) - lh) + hh) * h;
    _Float16 p2 = (((ll - hl) + lh) - hh) * h;
    _Float16 p3 = (((ll + hl) - lh) - hh) * h;
    _Float16 p4 = (((ll + hl) + lh) + hh) * h;
    int y = 2 * i, x = 2 * j;
    size_t rb = (size_t)b * 3136;
    cat[(rb + (size_t)y * 56 + x) * 640 + 512 + c]           = (float)p1;
    cat[(rb + (size_t)y * 56 + x + 1) * 640 + 512 + c]       = (float)p3;
    cat[(rb + (size_t)(y + 1) * 56 + x) * 640 + 512 + c]     = (float)p2;
    cat[(rb + (size_t)(y + 1) * 56 + x + 1) * 640 + 512 + c] = (float)p4;
}

// =====================================================================
// LayerNorm over C=512, one wave per row (4 rows / 256-thread block)
// =====================================================================
__global__ __launch_bounds__(256) void ln_kernel(
    float* __restrict__ p, const float* __restrict__ g,
    const float* __restrict__ bta)
{
    int wave = threadIdx.x >> 6;
    int lane = threadIdx.x & 63;
    int row = blockIdx.x * 4 + wave;            // 392*4 = 1568
    float* rp = p + (size_t)row * 512;
    float v[8];
    *(float4*)&v[0] = *(const float4*)(rp + lane * 8);
    *(float4*)&v[4] = *(const float4*)(rp + lane * 8 + 4);
    float s = ((v[0] + v[1]) + (v[2] + v[3])) + ((v[4] + v[5]) + (v[6] + v[7]));
#pragma unroll
    for (int off = 32; off; off >>= 1) s += __shfl_xor(s, off);
    float mu = s * (1.0f / 512.0f);
    float sq = 0.0f;
#pragma unroll
    for (int i = 0; i < 8; ++i) { v[i] -= mu; sq += v[i] * v[i]; }
#pragma unroll
    for (int off = 32; off; off >>= 1) sq += __shfl_xor(sq, off);
    float inv = 1.0f / sqrtf(sq * (1.0f / 512.0f) + 1e-5f);
    int c = lane * 8;
#pragma unroll
    for (int i = 0; i < 8; ++i) v[i] = v[i] * inv * g[c + i] + bta[c + i];
    *(float4*)(rp + c)     = *(float4*)&v[0];
    *(float4*)(rp + c + 4) = *(float4*)&v[4];
}

// =====================================================================
// Attention: per block = one (b, h) and 64 q rows; online softmax over
// m-chunks of 64 (196 = 64+64+64+4). q row in registers; k/v/p via LDS.
// Writes o into cat cols h*64..h*64+63.
// =====================================================================
__global__ __launch_bounds__(256) void attn_kernel(
    const float* __restrict__ q, const float* __restrict__ kv,
    float* __restrict__ cat)
{
    __shared__ float kc[64 * 68];   // k chunk, reused for v chunk
    __shared__ float pc[64 * 68];   // p chunk
    int bid = blockIdx.x;
    int tile = bid % 49;
    int h = (bid / 49) & 7;
    int b = bid / 392;
    int n0 = tile * 64;
    int t = threadIdx.x;
    int n = t >> 2;          // q row owned by this thread
    int quad = t & 3;        // m-subrange / d-subrange selector

    // load own q row (64 floats) into registers
    float qreg[64];
    {
        const float* src = q + ((size_t)(b * 3136 + n0 + n)) * 512 + h * 64;
#pragma unroll
        for (int d = 0; d < 64; d += 4)
            *(float4*)&qreg[d] = *(const float4*)(src + d);
    }

    float oacc[16];
#pragma unroll
    for (int i = 0; i < 16; ++i) oacc[i] = 0.0f;
    float mrun = -INFINITY, lrun = 0.0f;

    for (int c0 = 0; c0 < 196; c0 += 64) {
        int csz = 196 - c0; if (csz > 64) csz = 64;
        __syncthreads();   // previous PV done reading kc
        {   // load k chunk: row lr, 16 floats at (t&3)*16
            int lr = t >> 2, lo = (t & 3) * 16;
            if (lr < csz) {
                const float* src = kv + ((size_t)(b * 196 + c0 + lr)) * 1024 + h * 64 + lo;
#pragma unroll
                for (int u = 0; u < 16; u += 4)
                    *(float4*)&kc[lr * 68 + lo + u] = *(const float4*)(src + u);
            }
        }
        __syncthreads();

        // scores for m = quad*16 + i
        float s[16];
#pragma unroll
        for (int i = 0; i < 16; ++i) {
            const float* kp = &kc[(quad * 16 + i) * 68];
            float a = 0.0f;
#pragma unroll
            for (int d = 0; d < 64; d += 4) {
                float4 kq = *(const float4*)&kp[d];
                a += qreg[d] * kq.x + qreg[d + 1] * kq.y
                   + qreg[d + 2] * kq.z + qreg[d + 3] * kq.w;
            }
            s[i] = a * 0.125f;
        }
        if (csz < 64) {
#pragma unroll
            for (int i = 0; i < 16; ++i)
                if (quad * 16 + i >= csz) s[i] = -INFINITY;
        }

        // online softmax update (4 lanes per row cooperate via shuffles)
        float cmax = s[0];
#pragma unroll
        for (int i = 1; i < 16; ++i) cmax = fmaxf(cmax, s[i]);
        cmax = fmaxf(cmax, __shfl_xor(cmax, 1));
        cmax = fmaxf(cmax, __shfl_xor(cmax, 2));
        float mnew = fmaxf(mrun, cmax);
        float alpha = expf(mrun - mnew);   // 0 on first chunk (mrun=-inf)
        float psum = 0.0f;
#pragma unroll
        for (int i = 0; i < 16; ++i) {
            float pe = expf(s[i] - mnew);
            pc[n * 68 + quad * 16 + i] = pe;
            psum += pe;
        }
        psum += __shfl_xor(psum, 1);
        psum += __shfl_xor(psum, 2);
        lrun = lrun * alpha + psum;
        mrun = mnew;
#pragma unroll
        for (int i = 0; i < 16; ++i) oacc[i] *= alpha;

        __syncthreads();   // all done reading kc (k) and writing pc
        {   // load v chunk into kc
            int lr = t >> 2, lo = (t & 3) * 16;
            if (lr < csz) {
                const float* src = kv + ((size_t)(b * 196 + c0 + lr)) * 1024 + 512 + h * 64 + lo;
#pragma unroll
                for (int u = 0; u < 16; u += 4)
                    *(float4*)&kc[lr * 68 + lo + u] = *(const float4*)(src + u);
            }
        }
        __syncthreads();

        // PV: oacc[i] += sum_m p[n][m] * v[m][quad*16+i]
        const float* pp = &pc[n * 68];
#pragma unroll 4
        for (int m = 0; m < csz; ++m) {
            float pe = pp[m];
            const float* vp = &kc[m * 68 + quad * 16];
            float4 v0 = *(const float4*)&vp[0];
            float4 v1 = *(const float4*)&vp[4];
            float4 v2 = *(const float4*)&vp[8];
            float4 v3 = *(const float4*)&vp[12];
            oacc[0]  += pe * v0.x; oacc[1]  += pe * v0.y;
            oacc[2]  += pe * v0.z; oacc[3]  += pe * v0.w;
            oacc[4]  += pe * v1.x; oacc[5]  += pe * v1.y;
            oacc[6]  += pe * v1.z; oacc[7]  += pe * v1.w;
            oacc[8]  += pe * v2.x; oacc[9]  += pe * v2.y;
            oacc[10] += pe * v2.z; oacc[11] += pe * v2.w;
            oacc[12] += pe * v3.x; oacc[13] += pe * v3.y;
            oacc[14] += pe * v3.z; oacc[15] += pe * v3.w;
        }
    }

    float invl = 1.0f / lrun;
    float* dst = cat + ((size_t)(b * 3136 + n0 + n)) * 640 + h * 64 + quad * 16;
#pragma unroll
    for (int u = 0; u < 16; u += 4) {
        float4 o;
        o.x = oacc[u] * invl;     o.y = oacc[u + 1] * invl;
        o.z = oacc[u + 2] * invl; o.w = oacc[u + 3] * invl;
        *(float4*)(dst + u) = o;
    }
}

// =====================================================================
extern "C" void kernel_launch(void* const* d_in, const int* in_sizes, int n_in,
                              void* d_out, int out_size, void* d_ws, size_t ws_size,
                              hipStream_t stream)
{
    const float* x           = (const float*)d_in[0];
    // d_in[1], d_in[2] = H, W (56, 56) — hard-coded
    const float* reduce_w    = (const float*)d_in[3];
    const float* reduce_b    = (const float*)d_in[4];
    const float* reduce_g    = (const float*)d_in[5];
    const float* reduce_beta = (const float*)d_in[6];
    const float* filter_w    = (const float*)d_in[7];
    const float* filter_b    = (const float*)d_in[8];
    const float* filter_g    = (const float*)d_in[9];
    const float* filter_beta = (const float*)d_in[10];
    const float* q_w         = (const float*)d_in[11];
    const float* q_b         = (const float*)d_in[12];
    const float* ln_g        = (const float*)d_in[13];
    const float* ln_b        = (const float*)d_in[14];
    const float* kv_w        = (const float*)d_in[15];
    const float* kv_b        = (const float*)d_in[16];
    const float* kve_w       = (const float*)d_in[17];
    const float* kve_b       = (const float*)d_in[18];
    const float* proj_w      = (const float*)d_in[19];
    const float* proj_b      = (const float*)d_in[20];
    float* out = (float*)d_out;
    float* ws  = (float*)d_ws;

    float* q_buf = ws + OFF_Q;
    float* cat   = ws + OFF_CAT;
    float* rbuf  = ws + OFF_R;       // r (NHWC 128c); later reused as dwt_b
    float* dwt_a = ws + OFF_DWTA;    // later reused as kv_in
    float* kvbuf = ws + OFF_KV;
    float* wT    = ws + OFF_WT;
    float* kveT  = ws + OFF_KVET;
    float* dwt_b = rbuf;
    float* kv_in = dwt_a;

    // weight transposes (cheap, every call)
    transpose_filter<<<dim3(9216), dim3(256), 0, stream>>>(filter_w, wT);
    transpose_kve<<<dim3(4096), dim3(256), 0, stream>>>(kve_w, kveT);

    // q = x @ q_w.T + q_b   (25088 x 512)
    gemm_nt<0, 0><<<dim3(392, 8), dim3(256), 0, stream>>>(
        x, q_w, q_buf, 25088, 512, 512, 512, 512, q_b, nullptr, nullptr);

    // r = fp16(relu(bn(conv1x1(x))))   (25088 x 128, NHWC)
    gemm_nt<0, 1><<<dim3(392, 2), dim3(256), 0, stream>>>(
        x, reduce_w, rbuf, 25088, 512, 512, 512, 128,
        reduce_b, reduce_g, reduce_beta);

    // DWT (fp16 math)  -> dwt_a (B,28,28,512 NHWC)
    dwt_kernel<<<dim3(6272), dim3(128), 0, stream>>>(rbuf, dwt_a);

    // 3x3 conv + bn + relu + fp16-round -> dwt_b (aliases rbuf; rbuf is dead)
    gemm_nt<1, 1><<<dim3(98, 8), dim3(256), 0, stream>>>(
        dwt_a, wT, dwt_b, 6272, 4608, 0, 4608, 512,
        filter_b, filter_g, filter_beta);

    // IDWT -> cat cols 512..639
    idwt_kernel<<<dim3(6272), dim3(128), 0, stream>>>(dwt_b, cat);

    // kve 2x2 stride-2 conv -> kv_in (aliases dwt_a; dwt_a is dead)
    gemm_nt<2, 0><<<dim3(25, 8), dim3(256), 0, stream>>>(
        dwt_b, kveT, kv_in, 1568, 2048, 0, 2048, 512,
        kve_b, nullptr, nullptr);

    // LayerNorm in place
    ln_kernel<<<dim3(392), dim3(256), 0, stream>>>(kv_in, ln_g, ln_b);

    // kv = ln(kv_in) @ kv_w.T + kv_b   (1568 x 1024)
    gemm_nt<0, 0><<<dim3(25, 16), dim3(256), 0, stream>>>(
        kv_in, kv_w, kvbuf, 1568, 512, 512, 512, 1024,
        kv_b, nullptr, nullptr);

    // attention -> cat cols 0..511
    attn_kernel<<<dim3(3136), dim3(256), 0, stream>>>(q_buf, kvbuf, cat);

    // out = cat @ proj_w.T + proj_b   (25088 x 512)
    gemm_nt<0, 0><<<dim3(392, 8), dim3(256), 0, stream>>>(
        cat, proj_w, out, 25088, 640, 640, 640, 512,
        proj_b, nullptr, nullptr);
}

// Round 2
// 1442.921 us; speedup vs baseline: 1.3688x; 1.3688x over previous
//
#include <hip/hip_runtime.h>
#include <math.h>

// Problem constants: B=8, H=W=56, C=512, N=3136, c4=128, HEADS=8, hd=64, SR=2
// kv sequence length = 14*14 = 196

// ---------------- workspace layout (float offsets) ----------------
static const size_t OFF_Q    = 0;
static const size_t OFF_CAT  = 12845056;
static const size_t OFF_R    = 28901376;
static const size_t OFF_DWTA = 32112640;
static const size_t OFF_KV   = 35323904;
static const size_t OFF_WT   = 36929536;
static const size_t OFF_KVET = 39288832;
// total = 40,337,408 floats = 153.9 MB

// BN scale constant: 1/sqrt(1 + 1e-5)
#define BN_RSQ 0.9999950000374997f

// =====================================================================
// Generic NT GEMM: out[m][n] = sum_k A[m][k] * W[n][k]  (+ epilogue)
// ALOAD: 0 = plain row-major A (lda), 1 = conv3x3 implicit (NHWC 28x28, pad 1),
//        2 = kve 2x2 stride-2 implicit (NHWC 28x28 -> 14x14)
// EPI:   0 = +bias,   1 = +bias, BN(g,beta), ReLU, fp16-round
// Tile 64x64, BK=16, 256 threads, 4x4 per thread.
// =====================================================================
template <int ALOAD, int EPI>
__global__ __launch_bounds__(256) void gemm_nt(
    const float* __restrict__ A, const float* __restrict__ W,
    float* __restrict__ Cd, int M, int K, int lda, int ldw, int ldc,
    const float* __restrict__ bias, const float* __restrict__ bng,
    const float* __restrict__ bnb)
{
    __shared__ float As[16][68];
    __shared__ float Bs[16][68];
    const int t  = threadIdx.x;
    const int tx = t & 15, ty = t >> 4;
    const int m0 = blockIdx.x * 64, n0 = blockIdx.y * 64;
    const int lr = t >> 2;          // 0..63: tile row loaded by this thread
    const int lk = (t & 3) * 4;     // 0,4,8,12: k offset within chunk

    const int aRow = m0 + lr;
    bool rowValid = true;
    int bb = 0, yy = 0, xx = 0;
    if constexpr (ALOAD == 0) {
        rowValid = (aRow < M);
    } else if constexpr (ALOAD == 1) {  // m = b*784 + y*28 + x
        bb = aRow / 784; int rem = aRow - bb * 784;
        yy = rem / 28;   xx = rem - yy * 28;
    } else {                             // m = b*196 + i*14 + j
        rowValid = (aRow < M);
        int ar = rowValid ? aRow : 0;
        bb = ar / 196; int rem = ar - bb * 196;
        yy = rem / 14; xx = rem - yy * 14;
    }

    float acc[4][4];
#pragma unroll
    for (int i = 0; i < 4; ++i)
#pragma unroll
        for (int j = 0; j < 4; ++j) acc[i][j] = 0.0f;

    for (int k0 = 0; k0 < K; k0 += 16) {
        float4 av = make_float4(0.f, 0.f, 0.f, 0.f);
        float4 bv;
        if constexpr (ALOAD == 0) {
            if (rowValid)
                av = *(const float4*)(A + (size_t)aRow * lda + k0 + lk);
        } else if constexpr (ALOAD == 1) {
            int sub = k0 >> 9;            // (ky*3+kx), uniform per chunk
            int s3  = sub / 3;
            int dy  = s3 - 1, dx = (sub - s3 * 3) - 1;
            int y2 = yy + dy, x2 = xx + dx;
            if ((unsigned)y2 < 28u && (unsigned)x2 < 28u)
                av = *(const float4*)(A + ((size_t)(bb * 784 + y2 * 28 + x2)) * 512
                                        + (k0 & 511) + lk);
        } else {
            int sub = k0 >> 9;            // (ky*2+kx)
            int ky = sub >> 1, kx = sub & 1;
            int y2 = 2 * yy + ky, x2 = 2 * xx + kx;
            if (rowValid)
                av = *(const float4*)(A + ((size_t)(bb * 784 + y2 * 28 + x2)) * 512
                                        + (k0 & 511) + lk);
        }
        bv = *(const float4*)(W + (size_t)(n0 + lr) * ldw + k0 + lk);

        __syncthreads();   // previous iteration's compute done reading LDS
        As[lk + 0][lr] = av.x; As[lk + 1][lr] = av.y;
        As[lk + 2][lr] = av.z; As[lk + 3][lr] = av.w;
        Bs[lk + 0][lr] = bv.x; Bs[lk + 1][lr] = bv.y;
        Bs[lk + 2][lr] = bv.z; Bs[lk + 3][lr] = bv.w;
        __syncthreads();

#pragma unroll
        for (int kk = 0; kk < 16; ++kk) {
            float a[4], b[4];
            *(float4*)a = *(const float4*)&As[kk][ty * 4];
            *(float4*)b = *(const float4*)&Bs[kk][tx * 4];
#pragma unroll
            for (int i = 0; i < 4; ++i)
#pragma unroll
                for (int j = 0; j < 4; ++j) acc[i][j] += a[i] * b[j];
        }
    }

#pragma unroll
    for (int i = 0; i < 4; ++i) {
        int m = m0 + ty * 4 + i;
        if (m >= M) continue;
#pragma unroll
        for (int j = 0; j < 4; ++j) {
            int n = n0 + tx * 4 + j;
            float v = acc[i][j] + bias[n];
            if constexpr (EPI == 1) {
                v = v * (bng[n] * BN_RSQ) + bnb[n];
                v = fmaxf(v, 0.0f);
                v = (float)(_Float16)v;   // replicate .astype(fp16)
            }
            Cd[(size_t)m * ldc + n] = v;
        }
    }
}

// =====================================================================
// Weight transposes
// =====================================================================
__global__ __launch_bounds__(256) void transpose_filter(
    const float* __restrict__ fw, float* __restrict__ wT)
{   // wT[n][(ky*3+kx)*512 + ci] = fw[n][ci][ky][kx];  512*4608 elements
    int idx = blockIdx.x * 256 + threadIdx.x;
    int n = idx / 4608; int r = idx - n * 4608;
    int sub = r >> 9; int ci = r & 511;
    wT[idx] = fw[(size_t)n * 4608 + ci * 9 + sub];
}

__global__ __launch_bounds__(256) void transpose_kve(
    const float* __restrict__ kw, float* __restrict__ kT)
{   // kT[n][(ky*2+kx)*512 + ci] = kw[n][ci][ky][kx];  512*2048 elements
    int idx = blockIdx.x * 256 + threadIdx.x;
    int n = idx >> 11; int r = idx & 2047;
    int sub = r >> 9; int ci = r & 511;
    kT[idx] = kw[((size_t)n << 11) + (ci << 2) + sub];
}

// =====================================================================
// Haar DWT: r (B,56,56,128 NHWC, fp16-valued) -> dwt_a (B,28,28,512 NHWC)
// fp16 arithmetic, reference order: ((x1 op x2) op x3) op x4
// =====================================================================
__global__ __launch_bounds__(128) void dwt_kernel(
    const float* __restrict__ r, float* __restrict__ dwt)
{
    int bid = blockIdx.x;            // b*784 + i*28 + j
    int b = bid / 784; int rem = bid - b * 784;
    int i = rem / 28;  int j = rem - i * 28;
    int c = threadIdx.x;
    int y = 2 * i, x = 2 * j;
    size_t base = (size_t)b * 3136;
    float f1 = r[(base + (size_t)y * 56 + x) * 128 + c];           // (0::2,0::2)
    float f2 = r[(base + (size_t)(y + 1) * 56 + x) * 128 + c];     // (1::2,0::2)
    float f3 = r[(base + (size_t)y * 56 + (x + 1)) * 128 + c];     // (0::2,1::2)
    float f4 = r[(base + (size_t)(y + 1) * 56 + (x + 1)) * 128 + c];
    _Float16 h = (_Float16)0.5f;
    _Float16 x1 = (_Float16)f1 * h, x2 = (_Float16)f2 * h;
    _Float16 x3 = (_Float16)f3 * h, x4 = (_Float16)f4 * h;
    _Float16 ll = ((x1 + x2) + x3) + x4;
    _Float16 hl = (((-x1) - x2) + x3) + x4;
    _Float16 lh = (((-x1) + x2) - x3) + x4;
    _Float16 hh = ((x1 - x2) - x3) + x4;
    size_t ob = ((size_t)b * 784 + (size_t)i * 28 + j) * 512;
    dwt[ob + c]       = (float)ll;
    dwt[ob + 128 + c] = (float)hl;
    dwt[ob + 256 + c] = (float)lh;
    dwt[ob + 384 + c] = (float)hh;
}

// =====================================================================
// Haar IDWT: dwt_b (B,28,28,512 NHWC fp16-valued) -> cat cols 512..639
// =====================================================================
__global__ __launch_bounds__(128) void idwt_kernel(
    const float* __restrict__ d, float* __restrict__ cat)
{
    int bid = blockIdx.x;
    int b = bid / 784; int rem = bid - b * 784;
    int i = rem / 28;  int j = rem - i * 28;
    int c = threadIdx.x;
    size_t ib = ((size_t)b * 784 + (size_t)i * 28 + j) * 512;
    _Float16 ll = (_Float16)d[ib + c];
    _Float16 hl = (_Float16)d[ib + 128 + c];
    _Float16 lh = (_Float16)d[ib + 256 + c];
    _Float16 hh = (_Float16)d[ib + 384 + c];
    _Float16 h = (_Float16)0.5f;
    _Float16 p1 = (((ll - hl) - lh) + hh) * h;
    _Float16 p2 = (((ll - hl) + lh) - hh) * h;
    _Float16 p3 = (((ll + hl) - lh) - hh) * h;
    _Float16 p4 = (((ll + hl) + lh) + hh) * h;
    int y = 2 * i, x = 2 * j;
    size_t rb = (size_t)b * 3136;
    cat[(rb + (size_t)y * 56 + x) * 640 + 512 + c]           = (float)p1;
    cat[(rb + (size_t)y * 56 + x + 1) * 640 + 512 + c]       = (float)p3;
    cat[(rb + (size_t)(y + 1) * 56 + x) * 640 + 512 + c]     = (float)p2;
    cat[(rb + (size_t)(y + 1) * 56 + x + 1) * 640 + 512 + c] = (float)p4;
}

// =====================================================================
// LayerNorm over C=512, one wave per row (4 rows / 256-thread block)
// =====================================================================
__global__ __launch_bounds__(256) void ln_kernel(
    float* __restrict__ p, const float* __restrict__ g,
    const float* __restrict__ bta)
{
    int wave = threadIdx.x >> 6;
    int lane = threadIdx.x & 63;
    int row = blockIdx.x * 4 + wave;            // 392*4 = 1568
    float* rp = p + (size_t)row * 512;
    float v[8];
    *(float4*)&v[0] = *(const float4*)(rp + lane * 8);
    *(float4*)&v[4] = *(const float4*)(rp + lane * 8 + 4);
    float s = ((v[0] + v[1]) + (v[2] + v[3])) + ((v[4] + v[5]) + (v[6] + v[7]));
#pragma unroll
    for (int off = 32; off; off >>= 1) s += __shfl_xor(s, off);
    float mu = s * (1.0f / 512.0f);
    float sq = 0.0f;
#pragma unroll
    for (int i = 0; i < 8; ++i) { v[i] -= mu; sq += v[i] * v[i]; }
#pragma unroll
    for (int off = 32; off; off >>= 1) sq += __shfl_xor(sq, off);
    float inv = 1.0f / sqrtf(sq * (1.0f / 512.0f) + 1e-5f);
    int c = lane * 8;
#pragma unroll
    for (int i = 0; i < 8; ++i) v[i] = v[i] * inv * g[c + i] + bta[c + i];
    *(float4*)(rp + c)     = *(float4*)&v[0];
    *(float4*)(rp + c + 4) = *(float4*)&v[4];
}

// =====================================================================
// Attention, register-tiled. One block = (b, h, 64 q-rows).
// 16x16 thread grid; each thread owns a 4x4 score tile and 4x4 O tile.
// Online softmax over m-chunks of 64 (196 = 64+64+64+4).
// QK reads Qs[d][q] / KT[d][m] (transposed staging);
// PV reads Ps[m][q] / Vs[m][d] (V staged naturally, vector ds_writes).
// 16 FMA per 2 ds_read_b128 in both hot loops; reads are broadcast/2-way.
// Writes o into cat cols h*64..h*64+63.
// =====================================================================
__global__ __launch_bounds__(256) void attn_kernel(
    const float* __restrict__ q, const float* __restrict__ kv,
    float* __restrict__ cat)
{
    __shared__ float Qs[64][68];   // Q^T: [d][q]
    __shared__ float KT[64][68];   // K^T: [d][m] during QK; V: [m][d] during PV
    __shared__ float Ps[64][68];   // P^T: [m][q]
    int bid = blockIdx.x;
    int tile = bid % 49;
    int h = (bid / 49) & 7;
    int b = bid / 392;
    int n0 = tile * 64;
    int t  = threadIdx.x;
    int tx = t & 15, ty = t >> 4;
    int lr = t >> 2;              // staging row 0..63
    int lq = (t & 3) * 16;        // staging 16-col block offset

    // stage Q transposed: Qs[d][q]  (synced by the barrier before QK below)
    {
        const float* src = q + ((size_t)(b * 3136 + n0 + lr)) * 512 + h * 64 + lq;
        float v[16];
#pragma unroll
        for (int u = 0; u < 16; u += 4)
            *(float4*)&v[u] = *(const float4*)(src + u);
#pragma unroll
        for (int u = 0; u < 16; ++u) Qs[lq + u][lr] = v[u];
    }

    float oacc[4][4];
#pragma unroll
    for (int i = 0; i < 4; ++i)
#pragma unroll
        for (int j = 0; j < 4; ++j) oacc[i][j] = 0.0f;
    float mrun[4], lrun[4];
#pragma unroll
    for (int i = 0; i < 4; ++i) { mrun[i] = -INFINITY; lrun[i] = 0.0f; }

    for (int c0 = 0; c0 < 196; c0 += 64) {
        int csz = 196 - c0; if (csz > 64) csz = 64;
        __syncthreads();   // prev chunk's PV reads done (and Q writes visible)
        if (lr < csz) {    // stage K transposed: KT[d][m]
            const float* src = kv + ((size_t)(b * 196 + c0 + lr)) * 1024 + h * 64 + lq;
            float v[16];
#pragma unroll
            for (int u = 0; u < 16; u += 4)
                *(float4*)&v[u] = *(const float4*)(src + u);
#pragma unroll
            for (int u = 0; u < 16; ++u) KT[lq + u][lr] = v[u];
        }
        __syncthreads();

        // QK^T: s[i][j] = sum_d Q[ty*4+i][d] * K[tx*4+j][d], *scale
        float s[4][4];
#pragma unroll
        for (int i = 0; i < 4; ++i)
#pragma unroll
            for (int j = 0; j < 4; ++j) s[i][j] = 0.0f;
#pragma unroll 8
        for (int kk = 0; kk < 64; ++kk) {
            float a[4], bqv[4];
            *(float4*)a   = *(const float4*)&Qs[kk][ty * 4];
            *(float4*)bqv = *(const float4*)&KT[kk][tx * 4];
#pragma unroll
            for (int i = 0; i < 4; ++i)
#pragma unroll
                for (int j = 0; j < 4; ++j) s[i][j] += a[i] * bqv[j];
        }
#pragma unroll
        for (int i = 0; i < 4; ++i)
#pragma unroll
            for (int j = 0; j < 4; ++j) s[i][j] *= 0.125f;
        if (csz < 64) {
#pragma unroll
            for (int j = 0; j < 4; ++j)
                if (tx * 4 + j >= csz) {
#pragma unroll
                    for (int i = 0; i < 4; ++i) s[i][j] = -INFINITY;
                }
        }

        // online softmax update, rows ty*4+i; reduce across 16 tx lanes
#pragma unroll
        for (int i = 0; i < 4; ++i) {
            float rmax = fmaxf(fmaxf(s[i][0], s[i][1]), fmaxf(s[i][2], s[i][3]));
            rmax = fmaxf(rmax, __shfl_xor(rmax, 1));
            rmax = fmaxf(rmax, __shfl_xor(rmax, 2));
            rmax = fmaxf(rmax, __shfl_xor(rmax, 4));
            rmax = fmaxf(rmax, __shfl_xor(rmax, 8));
            float mnew = fmaxf(mrun[i], rmax);
            float alpha = __expf(mrun[i] - mnew);   // 0 on first chunk
            float rsum = 0.0f;
#pragma unroll
            for (int j = 0; j < 4; ++j) {
                s[i][j] = __expf(s[i][j] - mnew);
                rsum += s[i][j];
            }
            rsum += __shfl_xor(rsum, 1);
            rsum += __shfl_xor(rsum, 2);
            rsum += __shfl_xor(rsum, 4);
            rsum += __shfl_xor(rsum, 8);
            lrun[i] = lrun[i] * alpha + rsum;
            mrun[i] = mnew;
#pragma unroll
            for (int j = 0; j < 4; ++j) oacc[i][j] *= alpha;
        }

        __syncthreads();   // all QK reads of KT done before V overwrites it
        if (lr < csz) {    // stage V naturally: KT reused as Vs[m][d]
            const float* src = kv + ((size_t)(b * 196 + c0 + lr)) * 1024 + 512 + h * 64 + lq;
#pragma unroll
            for (int u = 0; u < 16; u += 4)
                *(float4*)&KT[lr][lq + u] = *(const float4*)(src + u);
        }
        // write P transposed: Ps[m][q]
#pragma unroll
        for (int i = 0; i < 4; ++i)
#pragma unroll
            for (int j = 0; j < 4; ++j)
                Ps[tx * 4 + j][ty * 4 + i] = s[i][j];
        __syncthreads();

        // PV: oacc[i][j] += sum_m P[q=ty*4+i][m] * V[m][d=tx*4+j]
        for (int m = 0; m < csz; ++m) {
            float pa[4], vb[4];
            *(float4*)pa = *(const float4*)&Ps[m][ty * 4];
            *(float4*)vb = *(const float4*)&KT[m][tx * 4];
#pragma unroll
            for (int i = 0; i < 4; ++i)
#pragma unroll
                for (int j = 0; j < 4; ++j) oacc[i][j] += pa[i] * vb[j];
        }
    }

    // epilogue: O /= l, write to cat cols h*64 + tx*4
#pragma unroll
    for (int i = 0; i < 4; ++i) {
        float inv = 1.0f / lrun[i];
        float* dst = cat + ((size_t)(b * 3136 + n0 + ty * 4 + i)) * 640 + h * 64 + tx * 4;
        float4 o;
        o.x = oacc[i][0] * inv; o.y = oacc[i][1] * inv;
        o.z = oacc[i][2] * inv; o.w = oacc[i][3] * inv;
        *(float4*)dst = o;
    }
}

// =====================================================================
extern "C" void kernel_launch(void* const* d_in, const int* in_sizes, int n_in,
                              void* d_out, int out_size, void* d_ws, size_t ws_size,
                              hipStream_t stream)
{
    const float* x           = (const float*)d_in[0];
    // d_in[1], d_in[2] = H, W (56, 56) — hard-coded
    const float* reduce_w    = (const float*)d_in[3];
    const float* reduce_b    = (const float*)d_in[4];
    const float* reduce_g    = (const float*)d_in[5];
    const float* reduce_beta = (const float*)d_in[6];
    const float* filter_w    = (const float*)d_in[7];
    const float* filter_b    = (const float*)d_in[8];
    const float* filter_g    = (const float*)d_in[9];
    const float* filter_beta = (const float*)d_in[10];
    const float* q_w         = (const float*)d_in[11];
    const float* q_b         = (const float*)d_in[12];
    const float* ln_g        = (const float*)d_in[13];
    const float* ln_b        = (const float*)d_in[14];
    const float* kv_w        = (const float*)d_in[15];
    const float* kv_b        = (const float*)d_in[16];
    const float* kve_w       = (const float*)d_in[17];
    const float* kve_b       = (const float*)d_in[18];
    const float* proj_w      = (const float*)d_in[19];
    const float* proj_b      = (const float*)d_in[20];
    float* out = (float*)d_out;
    float* ws  = (float*)d_ws;

    float* q_buf = ws + OFF_Q;
    float* cat   = ws + OFF_CAT;
    float* rbuf  = ws + OFF_R;       // r (NHWC 128c); later reused as dwt_b
    float* dwt_a = ws + OFF_DWTA;    // later reused as kv_in
    float* kvbuf = ws + OFF_KV;
    float* wT    = ws + OFF_WT;
    float* kveT  = ws + OFF_KVET;
    float* dwt_b = rbuf;
    float* kv_in = dwt_a;

    // weight transposes (cheap, every call)
    transpose_filter<<<dim3(9216), dim3(256), 0, stream>>>(filter_w, wT);
    transpose_kve<<<dim3(4096), dim3(256), 0, stream>>>(kve_w, kveT);

    // q = x @ q_w.T + q_b   (25088 x 512)
    gemm_nt<0, 0><<<dim3(392, 8), dim3(256), 0, stream>>>(
        x, q_w, q_buf, 25088, 512, 512, 512, 512, q_b, nullptr, nullptr);

    // r = fp16(relu(bn(conv1x1(x))))   (25088 x 128, NHWC)
    gemm_nt<0, 1><<<dim3(392, 2), dim3(256), 0, stream>>>(
        x, reduce_w, rbuf, 25088, 512, 512, 512, 128,
        reduce_b, reduce_g, reduce_beta);

    // DWT (fp16 math)  -> dwt_a (B,28,28,512 NHWC)
    dwt_kernel<<<dim3(6272), dim3(128), 0, stream>>>(rbuf, dwt_a);

    // 3x3 conv + bn + relu + fp16-round -> dwt_b (aliases rbuf; rbuf is dead)
    gemm_nt<1, 1><<<dim3(98, 8), dim3(256), 0, stream>>>(
        dwt_a, wT, dwt_b, 6272, 4608, 0, 4608, 512,
        filter_b, filter_g, filter_beta);

    // IDWT -> cat cols 512..639
    idwt_kernel<<<dim3(6272), dim3(128), 0, stream>>>(dwt_b, cat);

    // kve 2x2 stride-2 conv -> kv_in (aliases dwt_a; dwt_a is dead)
    gemm_nt<2, 0><<<dim3(25, 8), dim3(256), 0, stream>>>(
        dwt_b, kveT, kv_in, 1568, 2048, 0, 2048, 512,
        kve_b, nullptr, nullptr);

    // LayerNorm in place
    ln_kernel<<<dim3(392), dim3(256), 0, stream>>>(kv_in, ln_g, ln_b);

    // kv = ln(kv_in) @ kv_w.T + kv_b   (1568 x 1024)
    gemm_nt<0, 0><<<dim3(25, 16), dim3(256), 0, stream>>>(
        kv_in, kv_w, kvbuf, 1568, 512, 512, 512, 1024,
        kv_b, nullptr, nullptr);

    // attention -> cat cols 0..511
    attn_kernel<<<dim3(3136), dim3(256), 0, stream>>>(q_buf, kvbuf, cat);

    // out = cat @ proj_w.T + proj_b   (25088 x 512)
    gemm_nt<0, 0><<<dim3(392, 8), dim3(256), 0, stream>>>(
        cat, proj_w, out, 25088, 640, 640, 640, 512,
        proj_b, nullptr, nullptr);
}

// Round 3
// 666.324 us; speedup vs baseline: 2.9642x; 2.1655x over previous
//
#include <hip/hip_runtime.h>
#include <math.h>

// Problem constants: B=8, H=W=56, C=512, N=3136, c4=128, HEADS=8, hd=64, SR=2
// kv sequence length = 14*14 = 196

typedef _Float16 half8 __attribute__((ext_vector_type(8)));
typedef _Float16 half4v __attribute__((ext_vector_type(4)));
typedef float f32x4 __attribute__((ext_vector_type(4)));

// ---------------- workspace layout (offsets in halves; all 16B-aligned) ----
static const size_t OFF_X16  = 0;          // 25088*512
static const size_t OFF_Q16  = 12845056;   // 25088*512
static const size_t OFF_CAT  = 25690112;   // 25088*640
static const size_t OFF_R16  = 41746432;   // 25088*128
static const size_t OFF_PAD  = 44957696;   // 8*900*512  (30x30 zero-padded DWT)
static const size_t OFF_DWTB = 48644096;   // 8*784*512
static const size_t OFF_KVIN = 51855360;   // 1568*512 floats = 3,211,264 halves
static const size_t OFF_LN16 = 55066624;   // 1568*512
static const size_t OFF_KV16 = 55869440;   // 1568*1024
static const size_t OFF_WT   = 57475072;   // 512*4608
static const size_t OFF_KT   = 59834368;   // 512*2048
static const size_t OFF_QW   = 60882944;   // 512*512
static const size_t OFF_KVW  = 61145088;   // 1024*512
static const size_t OFF_PW   = 61669376;   // 512*640
static const size_t OFF_RW   = 61997056;   // 128*512
// total = 62,062,592 halves = 124.1 MB

#define BN_RSQ 0.9999950000374997f

__device__ __forceinline__ void async_copy16(const _Float16* g, _Float16* l) {
    __builtin_amdgcn_global_load_lds(
        (const __attribute__((address_space(1))) void*)g,
        (__attribute__((address_space(3))) void*)l, 16, 0, 0);
}

// =====================================================================
// MFMA fp16 NT GEMM: out[m][n] = sum_k A[m][k]*W[n][k] (+ epilogue)
// ALOAD: 0 plain row-major (lda), 1 conv3x3 on padded 30x30x512 NHWC,
//        2 kve 2x2 stride-2 on 28x28x512 NHWC
// EPI:   0 = +bias -> fp32, 1 = +bias,BN,ReLU -> fp16, 2 = +bias -> fp16
// 128x128 tile, BK=32, 256 threads (4 waves 2x2), 16x16x32 MFMA.
// =====================================================================
template <int ALOAD, int EPI>
__global__ __launch_bounds__(256) void gemm16(
    const _Float16* __restrict__ A, const _Float16* __restrict__ W,
    void* __restrict__ outp, int M, int K, int lda, int ldc,
    const float* __restrict__ bias, const float* __restrict__ bng,
    const float* __restrict__ bnb)
{
    __shared__ _Float16 sA[128 * 32];
    __shared__ _Float16 sB[128 * 32];
    const int t = threadIdx.x;
    const int lane = t & 63, wid = t >> 6;
    const int m0 = blockIdx.x * 128, n0 = blockIdx.y * 128;

    const int sr = wid * 16 + (lane >> 2);   // staging tile row (instr0)
    const int sc = (lane & 3) * 8;           // staging col offset (halves)
    _Float16* ldsA0 = sA + wid * 512;
    _Float16* ldsA1 = sA + 2048 + wid * 512;
    _Float16* ldsB0 = sB + wid * 512;
    _Float16* ldsB1 = sB + 2048 + wid * 512;

    const _Float16 *aP0, *aP1;
    if constexpr (ALOAD == 0) {
        int r0 = m0 + sr;      if (r0 > M - 1) r0 = M - 1;
        int r1 = m0 + 64 + sr; if (r1 > M - 1) r1 = M - 1;
        aP0 = A + (size_t)r0 * lda + sc;
        aP1 = A + (size_t)r1 * lda + sc;
    } else if constexpr (ALOAD == 1) {
        int m_ = m0 + sr;
        int b_ = m_ / 784, rem = m_ - b_ * 784, y_ = rem / 28, x_ = rem - y_ * 28;
        aP0 = A + ((size_t)(b_ * 900 + (y_ + 1) * 30 + (x_ + 1))) * 512 + sc;
        m_ = m0 + 64 + sr;
        b_ = m_ / 784; rem = m_ - b_ * 784; y_ = rem / 28; x_ = rem - y_ * 28;
        aP1 = A + ((size_t)(b_ * 900 + (y_ + 1) * 30 + (x_ + 1))) * 512 + sc;
    } else {
        int m_ = m0 + sr; if (m_ > M - 1) m_ = M - 1;
        int b_ = m_ / 196, rem = m_ - b_ * 196, i_ = rem / 14, j_ = rem - i_ * 14;
        aP0 = A + ((size_t)(b_ * 784 + 2 * i_ * 28 + 2 * j_)) * 512 + sc;
        m_ = m0 + 64 + sr; if (m_ > M - 1) m_ = M - 1;
        b_ = m_ / 196; rem = m_ - b_ * 196; i_ = rem / 14; j_ = rem - i_ * 14;
        aP1 = A + ((size_t)(b_ * 784 + 2 * i_ * 28 + 2 * j_)) * 512 + sc;
    }
    const _Float16* bP0 = W + (size_t)(n0 + sr) * K + sc;
    const _Float16* bP1 = W + (size_t)(n0 + 64 + sr) * K + sc;

    const int mw = wid & 1, nw = wid >> 1;
    const _Float16* pA = sA + (mw * 64 + (lane & 15)) * 32 + (lane >> 4) * 8;
    const _Float16* pB = sB + (nw * 64 + (lane & 15)) * 32 + (lane >> 4) * 8;

    f32x4 acc[4][4];
#pragma unroll
    for (int i = 0; i < 4; ++i)
#pragma unroll
        for (int j = 0; j < 4; ++j) acc[i][j] = (f32x4)(0.0f);

    for (int k0 = 0; k0 < K; k0 += 32) {
        int aOff;
        if constexpr (ALOAD == 0) {
            aOff = k0;
        } else if constexpr (ALOAD == 1) {
            int sub = k0 >> 9; int s3 = sub / 3;
            int dy = s3 - 1, dx = sub - s3 * 3 - 1;
            aOff = (dy * 30 + dx) * 512 + (k0 & 511);
        } else {
            int sub = k0 >> 9; int ky = sub >> 1, kx = sub & 1;
            aOff = (ky * 28 + kx) * 512 + (k0 & 511);
        }
        __syncthreads();   // prior iteration's ds_reads done before overwrite
        async_copy16(aP0 + aOff, ldsA0);
        async_copy16(aP1 + aOff, ldsA1);
        async_copy16(bP0 + k0, ldsB0);
        async_copy16(bP1 + k0, ldsB1);
        __syncthreads();   // vmcnt(0) drain -> staged data visible

        half8 aF[4], bF[4];
#pragma unroll
        for (int i = 0; i < 4; ++i) aF[i] = *(const half8*)(pA + i * 512);
#pragma unroll
        for (int j = 0; j < 4; ++j) bF[j] = *(const half8*)(pB + j * 512);
#pragma unroll
        for (int i = 0; i < 4; ++i)
#pragma unroll
            for (int j = 0; j < 4; ++j)
                acc[i][j] = __builtin_amdgcn_mfma_f32_16x16x32_f16(
                    aF[i], bF[j], acc[i][j], 0, 0, 0);
    }

    // epilogue: C/D layout col=lane&15, row=(lane>>4)*4+reg
    const int orow = m0 + mw * 64 + (lane >> 4) * 4;
    const int ocol = n0 + nw * 64 + (lane & 15);
#pragma unroll
    for (int j = 0; j < 4; ++j) {
        int col = ocol + j * 16;
        float bv = bias[col];
        float g = 0.0f, b2 = 0.0f;
        if constexpr (EPI == 1) { g = bng[col] * BN_RSQ; b2 = bnb[col]; }
#pragma unroll
        for (int i = 0; i < 4; ++i) {
#pragma unroll
            for (int r = 0; r < 4; ++r) {
                int row = orow + i * 16 + r;
                if (row >= M) continue;
                float v = acc[i][j][r] + bv;
                if constexpr (EPI == 1) v = fmaxf(v * g + b2, 0.0f);
                if constexpr (EPI == 0)
                    ((float*)outp)[(size_t)row * ldc + col] = v;
                else
                    ((_Float16*)outp)[(size_t)row * ldc + col] = (_Float16)v;
            }
        }
    }
}

// =====================================================================
// small utility kernels
// =====================================================================
__global__ __launch_bounds__(256) void cvt_f32_f16(
    const float* __restrict__ s, _Float16* __restrict__ d, int n8)
{
    int i = blockIdx.x * 256 + threadIdx.x;
    if (i >= n8) return;
    const float4* sp = (const float4*)(s + (size_t)i * 8);
    float4 a = sp[0], b = sp[1];
    half8 h;
    h[0] = (_Float16)a.x; h[1] = (_Float16)a.y; h[2] = (_Float16)a.z; h[3] = (_Float16)a.w;
    h[4] = (_Float16)b.x; h[5] = (_Float16)b.y; h[6] = (_Float16)b.z; h[7] = (_Float16)b.w;
    *(half8*)(d + (size_t)i * 8) = h;
}

__global__ __launch_bounds__(256) void zero_half(_Float16* __restrict__ p, int n8)
{
    int i = blockIdx.x * 256 + threadIdx.x;
    if (i < n8) *(float4*)(p + (size_t)i * 8) = make_float4(0.f, 0.f, 0.f, 0.f);
}

__global__ __launch_bounds__(256) void transpose_filter16(
    const float* __restrict__ fw, _Float16* __restrict__ wT)
{   // wT[n][(ky*3+kx)*512 + ci] = fw[n][ci][ky][kx]; 512*4608
    int idx = blockIdx.x * 256 + threadIdx.x;
    int n = idx / 4608; int r = idx - n * 4608;
    int sub = r >> 9; int ci = r & 511;
    wT[idx] = (_Float16)fw[(size_t)n * 4608 + ci * 9 + sub];
}

__global__ __launch_bounds__(256) void transpose_kve16(
    const float* __restrict__ kw, _Float16* __restrict__ kT)
{   // kT[n][(ky*2+kx)*512 + ci] = kw[n][ci][ky][kx]; 512*2048
    int idx = blockIdx.x * 256 + threadIdx.x;
    int n = idx >> 11; int r = idx & 2047;
    int sub = r >> 9; int ci = r & 511;
    kT[idx] = (_Float16)kw[((size_t)n << 11) + (ci << 2) + sub];
}

// =====================================================================
// Haar DWT: rbuf16 (B,56,56,128 NHWC fp16) -> padded (B,30,30,512 NHWC fp16)
// writes interior pixel (i+1, j+1); border pre-zeroed
// =====================================================================
__global__ __launch_bounds__(128) void dwt_kernel(
    const _Float16* __restrict__ r, _Float16* __restrict__ pad)
{
    int bid = blockIdx.x;            // b*784 + i*28 + j
    int b = bid / 784; int rem = bid - b * 784;
    int i = rem / 28;  int j = rem - i * 28;
    int c = threadIdx.x;
    int y = 2 * i, x = 2 * j;
    size_t base = (size_t)b * 3136;
    _Float16 f1 = r[(base + (size_t)y * 56 + x) * 128 + c];
    _Float16 f2 = r[(base + (size_t)(y + 1) * 56 + x) * 128 + c];
    _Float16 f3 = r[(base + (size_t)y * 56 + (x + 1)) * 128 + c];
    _Float16 f4 = r[(base + (size_t)(y + 1) * 56 + (x + 1)) * 128 + c];
    _Float16 h = (_Float16)0.5f;
    _Float16 x1 = f1 * h, x2 = f2 * h, x3 = f3 * h, x4 = f4 * h;
    _Float16 ll = ((x1 + x2) + x3) + x4;
    _Float16 hl = (((-x1) - x2) + x3) + x4;
    _Float16 lh = (((-x1) + x2) - x3) + x4;
    _Float16 hh = ((x1 - x2) - x3) + x4;
    size_t ob = ((size_t)b * 900 + (size_t)(i + 1) * 30 + (j + 1)) * 512;
    pad[ob + c]       = ll;
    pad[ob + 128 + c] = hl;
    pad[ob + 256 + c] = lh;
    pad[ob + 384 + c] = hh;
}

// =====================================================================
// Haar IDWT: dwt_b16 (B,28,28,512 NHWC fp16) -> cat16 cols 512..639
// =====================================================================
__global__ __launch_bounds__(128) void idwt_kernel(
    const _Float16* __restrict__ d, _Float16* __restrict__ cat)
{
    int bid = blockIdx.x;
    int b = bid / 784; int rem = bid - b * 784;
    int i = rem / 28;  int j = rem - i * 28;
    int c = threadIdx.x;
    size_t ib = ((size_t)b * 784 + (size_t)i * 28 + j) * 512;
    _Float16 ll = d[ib + c];
    _Float16 hl = d[ib + 128 + c];
    _Float16 lh = d[ib + 256 + c];
    _Float16 hh = d[ib + 384 + c];
    _Float16 h = (_Float16)0.5f;
    _Float16 p1 = (((ll - hl) - lh) + hh) * h;
    _Float16 p2 = (((ll - hl) + lh) - hh) * h;
    _Float16 p3 = (((ll + hl) - lh) - hh) * h;
    _Float16 p4 = (((ll + hl) + lh) + hh) * h;
    int y = 2 * i, x = 2 * j;
    size_t rb = (size_t)b * 3136;
    cat[(rb + (size_t)y * 56 + x) * 640 + 512 + c]           = p1;
    cat[(rb + (size_t)y * 56 + x + 1) * 640 + 512 + c]       = p3;
    cat[(rb + (size_t)(y + 1) * 56 + x) * 640 + 512 + c]     = p2;
    cat[(rb + (size_t)(y + 1) * 56 + x + 1) * 640 + 512 + c] = p4;
}

// =====================================================================
// LayerNorm over C=512 (fp32 in, fp16 out), one wave per row
// =====================================================================
__global__ __launch_bounds__(256) void ln_kernel(
    const float* __restrict__ p, _Float16* __restrict__ o,
    const float* __restrict__ g, const float* __restrict__ bta)
{
    int wave = threadIdx.x >> 6;
    int lane = threadIdx.x & 63;
    int row = blockIdx.x * 4 + wave;            // 392*4 = 1568
    const float* rp = p + (size_t)row * 512;
    float v[8];
    *(float4*)&v[0] = *(const float4*)(rp + lane * 8);
    *(float4*)&v[4] = *(const float4*)(rp + lane * 8 + 4);
    float s = ((v[0] + v[1]) + (v[2] + v[3])) + ((v[4] + v[5]) + (v[6] + v[7]));
#pragma unroll
    for (int off = 32; off; off >>= 1) s += __shfl_xor(s, off);
    float mu = s * (1.0f / 512.0f);
    float sq = 0.0f;
#pragma unroll
    for (int i = 0; i < 8; ++i) { v[i] -= mu; sq += v[i] * v[i]; }
#pragma unroll
    for (int off = 32; off; off >>= 1) sq += __shfl_xor(sq, off);
    float inv = 1.0f / sqrtf(sq * (1.0f / 512.0f) + 1e-5f);
    int c = lane * 8;
    half8 hv;
#pragma unroll
    for (int i = 0; i < 8; ++i) hv[i] = (_Float16)(v[i] * inv * g[c + i] + bta[c + i]);
    *(half8*)(o + (size_t)row * 512 + c) = hv;
}

// =====================================================================
// Attention, register-tiled, fp16 I/O, fp32 math. One block = (b,h,64 q).
// =====================================================================
__global__ __launch_bounds__(256) void attn_kernel(
    const _Float16* __restrict__ q, const _Float16* __restrict__ kv,
    _Float16* __restrict__ cat)
{
    __shared__ float Qs[64][68];   // Q^T [d][q]
    __shared__ float KT[64][68];   // K^T [d][m] during QK; V [m][d] during PV
    __shared__ float Ps[64][68];   // P^T [m][q]
    int bid = blockIdx.x;
    int tile = bid % 49;
    int h = (bid / 49) & 7;
    int b = bid / 392;
    int n0 = tile * 64;
    int t  = threadIdx.x;
    int tx = t & 15, ty = t >> 4;
    int lr = t >> 2;
    int lq = (t & 3) * 16;

    {   // stage Q transposed (fp16 -> fp32)
        const _Float16* src = q + ((size_t)(b * 3136 + n0 + lr)) * 512 + h * 64 + lq;
        half8 v0 = *(const half8*)src, v1 = *(const half8*)(src + 8);
#pragma unroll
        for (int u = 0; u < 8; ++u) {
            Qs[lq + u][lr]     = (float)v0[u];
            Qs[lq + 8 + u][lr] = (float)v1[u];
        }
    }

    float oacc[4][4];
#pragma unroll
    for (int i = 0; i < 4; ++i)
#pragma unroll
        for (int j = 0; j < 4; ++j) oacc[i][j] = 0.0f;
    float mrun[4], lrun[4];
#pragma unroll
    for (int i = 0; i < 4; ++i) { mrun[i] = -INFINITY; lrun[i] = 0.0f; }

    for (int c0 = 0; c0 < 196; c0 += 64) {
        int csz = 196 - c0; if (csz > 64) csz = 64;
        __syncthreads();
        if (lr < csz) {    // stage K transposed
            const _Float16* src = kv + ((size_t)(b * 196 + c0 + lr)) * 1024 + h * 64 + lq;
            half8 v0 = *(const half8*)src, v1 = *(const half8*)(src + 8);
#pragma unroll
            for (int u = 0; u < 8; ++u) {
                KT[lq + u][lr]     = (float)v0[u];
                KT[lq + 8 + u][lr] = (float)v1[u];
            }
        }
        __syncthreads();

        float s[4][4];
#pragma unroll
        for (int i = 0; i < 4; ++i)
#pragma unroll
            for (int j = 0; j < 4; ++j) s[i][j] = 0.0f;
#pragma unroll 8
        for (int kk = 0; kk < 64; ++kk) {
            float a[4], bq[4];
            *(float4*)a  = *(const float4*)&Qs[kk][ty * 4];
            *(float4*)bq = *(const float4*)&KT[kk][tx * 4];
#pragma unroll
            for (int i = 0; i < 4; ++i)
#pragma unroll
                for (int j = 0; j < 4; ++j) s[i][j] += a[i] * bq[j];
        }
#pragma unroll
        for (int i = 0; i < 4; ++i)
#pragma unroll
            for (int j = 0; j < 4; ++j) s[i][j] *= 0.125f;
        if (csz < 64) {
#pragma unroll
            for (int j = 0; j < 4; ++j)
                if (tx * 4 + j >= csz) {
#pragma unroll
                    for (int i = 0; i < 4; ++i) s[i][j] = -INFINITY;
                }
        }

#pragma unroll
        for (int i = 0; i < 4; ++i) {
            float rmax = fmaxf(fmaxf(s[i][0], s[i][1]), fmaxf(s[i][2], s[i][3]));
            rmax = fmaxf(rmax, __shfl_xor(rmax, 1));
            rmax = fmaxf(rmax, __shfl_xor(rmax, 2));
            rmax = fmaxf(rmax, __shfl_xor(rmax, 4));
            rmax = fmaxf(rmax, __shfl_xor(rmax, 8));
            float mnew = fmaxf(mrun[i], rmax);
            float alpha = __expf(mrun[i] - mnew);
            float rsum = 0.0f;
#pragma unroll
            for (int j = 0; j < 4; ++j) {
                s[i][j] = __expf(s[i][j] - mnew);
                rsum += s[i][j];
            }
            rsum += __shfl_xor(rsum, 1);
            rsum += __shfl_xor(rsum, 2);
            rsum += __shfl_xor(rsum, 4);
            rsum += __shfl_xor(rsum, 8);
            lrun[i] = lrun[i] * alpha + rsum;
            mrun[i] = mnew;
#pragma unroll
            for (int j = 0; j < 4; ++j) oacc[i][j] *= alpha;
        }

        __syncthreads();
        if (lr < csz) {    // stage V naturally
            const _Float16* src = kv + ((size_t)(b * 196 + c0 + lr)) * 1024 + 512 + h * 64 + lq;
            half8 v0 = *(const half8*)src, v1 = *(const half8*)(src + 8);
#pragma unroll
            for (int u = 0; u < 8; ++u) {
                KT[lr][lq + u]     = (float)v0[u];
                KT[lr][lq + 8 + u] = (float)v1[u];
            }
        }
#pragma unroll
        for (int i = 0; i < 4; ++i)
#pragma unroll
            for (int j = 0; j < 4; ++j)
                Ps[tx * 4 + j][ty * 4 + i] = s[i][j];
        __syncthreads();

        for (int m = 0; m < csz; ++m) {
            float pa[4], vb[4];
            *(float4*)pa = *(const float4*)&Ps[m][ty * 4];
            *(float4*)vb = *(const float4*)&KT[m][tx * 4];
#pragma unroll
            for (int i = 0; i < 4; ++i)
#pragma unroll
                for (int j = 0; j < 4; ++j) oacc[i][j] += pa[i] * vb[j];
        }
    }

#pragma unroll
    for (int i = 0; i < 4; ++i) {
        float inv = 1.0f / lrun[i];
        _Float16* dst = cat + ((size_t)(b * 3136 + n0 + ty * 4 + i)) * 640 + h * 64 + tx * 4;
        half4v o;
        o[0] = (_Float16)(oacc[i][0] * inv);
        o[1] = (_Float16)(oacc[i][1] * inv);
        o[2] = (_Float16)(oacc[i][2] * inv);
        o[3] = (_Float16)(oacc[i][3] * inv);
        *(half4v*)dst = o;
    }
}

// =====================================================================
extern "C" void kernel_launch(void* const* d_in, const int* in_sizes, int n_in,
                              void* d_out, int out_size, void* d_ws, size_t ws_size,
                              hipStream_t stream)
{
    const float* x           = (const float*)d_in[0];
    const float* reduce_w    = (const float*)d_in[3];
    const float* reduce_b    = (const float*)d_in[4];
    const float* reduce_g    = (const float*)d_in[5];
    const float* reduce_beta = (const float*)d_in[6];
    const float* filter_w    = (const float*)d_in[7];
    const float* filter_b    = (const float*)d_in[8];
    const float* filter_g    = (const float*)d_in[9];
    const float* filter_beta = (const float*)d_in[10];
    const float* q_w         = (const float*)d_in[11];
    const float* q_b         = (const float*)d_in[12];
    const float* ln_g        = (const float*)d_in[13];
    const float* ln_b        = (const float*)d_in[14];
    const float* kv_w        = (const float*)d_in[15];
    const float* kv_b        = (const float*)d_in[16];
    const float* kve_w       = (const float*)d_in[17];
    const float* kve_b       = (const float*)d_in[18];
    const float* proj_w      = (const float*)d_in[19];
    const float* proj_b      = (const float*)d_in[20];
    float* out = (float*)d_out;
    _Float16* hws = (_Float16*)d_ws;

    _Float16* x16    = hws + OFF_X16;
    _Float16* q16    = hws + OFF_Q16;
    _Float16* cat16  = hws + OFF_CAT;
    _Float16* r16    = hws + OFF_R16;
    _Float16* pad16  = hws + OFF_PAD;
    _Float16* dwtb16 = hws + OFF_DWTB;
    float*    kv_in  = (float*)(hws + OFF_KVIN);
    _Float16* ln16   = hws + OFF_LN16;
    _Float16* kv16   = hws + OFF_KV16;
    _Float16* wT16   = hws + OFF_WT;
    _Float16* kT16   = hws + OFF_KT;
    _Float16* qw16   = hws + OFF_QW;
    _Float16* kvw16  = hws + OFF_KVW;
    _Float16* pw16   = hws + OFF_PW;
    _Float16* rw16   = hws + OFF_RW;

    // conversions / transposes / padding init
    cvt_f32_f16<<<dim3(6272), dim3(256), 0, stream>>>(x, x16, 1605632);
    cvt_f32_f16<<<dim3(128),  dim3(256), 0, stream>>>(q_w, qw16, 32768);
    cvt_f32_f16<<<dim3(256),  dim3(256), 0, stream>>>(kv_w, kvw16, 65536);
    cvt_f32_f16<<<dim3(160),  dim3(256), 0, stream>>>(proj_w, pw16, 40960);
    cvt_f32_f16<<<dim3(32),   dim3(256), 0, stream>>>(reduce_w, rw16, 8192);
    transpose_filter16<<<dim3(9216), dim3(256), 0, stream>>>(filter_w, wT16);
    transpose_kve16<<<dim3(4096), dim3(256), 0, stream>>>(kve_w, kT16);
    zero_half<<<dim3(1800), dim3(256), 0, stream>>>(pad16, 460800);

    // q = x @ q_w.T + q_b  -> fp16
    gemm16<0, 2><<<dim3(196, 4), dim3(256), 0, stream>>>(
        x16, qw16, q16, 25088, 512, 512, 512, q_b, nullptr, nullptr);

    // r = fp16(relu(bn(conv1x1(x))))  (25088 x 128 NHWC fp16)
    gemm16<0, 1><<<dim3(196, 1), dim3(256), 0, stream>>>(
        x16, rw16, r16, 25088, 512, 512, 128, reduce_b, reduce_g, reduce_beta);

    // DWT -> padded 30x30x512
    dwt_kernel<<<dim3(6272), dim3(128), 0, stream>>>(r16, pad16);

    // 3x3 conv + bn + relu + fp16 -> dwt_b
    gemm16<1, 1><<<dim3(49, 4), dim3(256), 0, stream>>>(
        pad16, wT16, dwtb16, 6272, 4608, 0, 512, filter_b, filter_g, filter_beta);

    // IDWT -> cat cols 512..639
    idwt_kernel<<<dim3(6272), dim3(128), 0, stream>>>(dwtb16, cat16);

    // kve 2x2 s2 conv -> kv_in (fp32)
    gemm16<2, 0><<<dim3(13, 4), dim3(256), 0, stream>>>(
        dwtb16, kT16, kv_in, 1568, 2048, 0, 512, kve_b, nullptr, nullptr);

    // LayerNorm -> fp16
    ln_kernel<<<dim3(392), dim3(256), 0, stream>>>(kv_in, ln16, ln_g, ln_b);

    // kv = ln @ kv_w.T + kv_b -> fp16 (1568 x 1024)
    gemm16<0, 2><<<dim3(13, 8), dim3(256), 0, stream>>>(
        ln16, kvw16, kv16, 1568, 512, 512, 1024, kv_b, nullptr, nullptr);

    // attention -> cat cols 0..511
    attn_kernel<<<dim3(3136), dim3(256), 0, stream>>>(q16, kv16, cat16);

    // out = cat @ proj_w.T + proj_b  (fp32)
    gemm16<0, 0><<<dim3(196, 4), dim3(256), 0, stream>>>(
        cat16, pw16, out, 25088, 640, 640, 512, proj_b, nullptr, nullptr);
}

// Round 4
// 532.643 us; speedup vs baseline: 3.7081x; 1.2510x over previous
//
#include <hip/hip_runtime.h>
#include <math.h>

// Problem constants: B=8, H=W=56, C=512, N=3136, c4=128, HEADS=8, hd=64, SR=2
// kv sequence length = 14*14 = 196 (padded to 224 for attention)

typedef _Float16 half8 __attribute__((ext_vector_type(8)));
typedef _Float16 half4v __attribute__((ext_vector_type(4)));
typedef float f32x4 __attribute__((ext_vector_type(4)));

// ---------------- workspace layout (offsets in halves; all 16B-aligned) ----
static const size_t OFF_X16  = 0;          // 25088*512
static const size_t OFF_Q16  = 12845056;   // 25088*512
static const size_t OFF_CAT  = 25690112;   // 25088*640
static const size_t OFF_R16  = 41746432;   // 25088*128
static const size_t OFF_PAD  = 44957696;   // 8*900*512  (30x30 zero-padded DWT)
static const size_t OFF_DWTB = 48644096;   // 8*784*512
static const size_t OFF_KVIN = 51855360;   // 1568*512 floats = 3,211,264 halves
static const size_t OFF_LN16 = 55066624;   // 1568*512
static const size_t OFF_KV16 = 55869440;   // 1568*1024
static const size_t OFF_WT   = 57475072;   // 512*4608
static const size_t OFF_KT   = 59834368;   // 512*2048
static const size_t OFF_QW   = 60882944;   // 512*512
static const size_t OFF_KVW  = 61145088;   // 1024*512
static const size_t OFF_PW   = 61669376;   // 512*640
static const size_t OFF_RW   = 61997056;   // 128*512
static const size_t OFF_VT   = 62062592;   // 8*8*64*224 = 917504 (V^T, m-padded)
// total = 62,980,096 halves = 126.0 MB

#define BN_RSQ 0.9999950000374997f
#define SCL2   0.1803368801111204f   /* 0.125 * log2(e) */

__device__ __forceinline__ void async_copy16(const _Float16* g, _Float16* l) {
    __builtin_amdgcn_global_load_lds(
        (const __attribute__((address_space(1))) void*)g,
        (__attribute__((address_space(3))) void*)l, 16, 0, 0);
}

// =====================================================================
// MFMA fp16 NT GEMM: out[m][n] = sum_k A[m][k]*W[n][k] (+ epilogue)
// ALOAD: 0 plain row-major (lda), 1 conv3x3 on padded 30x30x512 NHWC,
//        2 kve 2x2 stride-2 on 28x28x512 NHWC
// EPI:   0 = +bias -> fp32, 1 = +bias,BN,ReLU -> fp16, 2 = +bias -> fp16
// 128x128 tile, BK=32, 256 threads (4 waves 2x2), 16x16x32 MFMA.
// =====================================================================
template <int ALOAD, int EPI>
__global__ __launch_bounds__(256) void gemm16(
    const _Float16* __restrict__ A, const _Float16* __restrict__ W,
    void* __restrict__ outp, int M, int K, int lda, int ldc,
    const float* __restrict__ bias, const float* __restrict__ bng,
    const float* __restrict__ bnb)
{
    __shared__ _Float16 sA[128 * 32];
    __shared__ _Float16 sB[128 * 32];
    const int t = threadIdx.x;
    const int lane = t & 63, wid = t >> 6;
    const int m0 = blockIdx.x * 128, n0 = blockIdx.y * 128;

    const int sr = wid * 16 + (lane >> 2);   // staging tile row (instr0)
    const int sc = (lane & 3) * 8;           // staging col offset (halves)
    _Float16* ldsA0 = sA + wid * 512;
    _Float16* ldsA1 = sA + 2048 + wid * 512;
    _Float16* ldsB0 = sB + wid * 512;
    _Float16* ldsB1 = sB + 2048 + wid * 512;

    const _Float16 *aP0, *aP1;
    if constexpr (ALOAD == 0) {
        int r0 = m0 + sr;      if (r0 > M - 1) r0 = M - 1;
        int r1 = m0 + 64 + sr; if (r1 > M - 1) r1 = M - 1;
        aP0 = A + (size_t)r0 * lda + sc;
        aP1 = A + (size_t)r1 * lda + sc;
    } else if constexpr (ALOAD == 1) {
        int m_ = m0 + sr;
        int b_ = m_ / 784, rem = m_ - b_ * 784, y_ = rem / 28, x_ = rem - y_ * 28;
        aP0 = A + ((size_t)(b_ * 900 + (y_ + 1) * 30 + (x_ + 1))) * 512 + sc;
        m_ = m0 + 64 + sr;
        b_ = m_ / 784; rem = m_ - b_ * 784; y_ = rem / 28; x_ = rem - y_ * 28;
        aP1 = A + ((size_t)(b_ * 900 + (y_ + 1) * 30 + (x_ + 1))) * 512 + sc;
    } else {
        int m_ = m0 + sr; if (m_ > M - 1) m_ = M - 1;
        int b_ = m_ / 196, rem = m_ - b_ * 196, i_ = rem / 14, j_ = rem - i_ * 14;
        aP0 = A + ((size_t)(b_ * 784 + 2 * i_ * 28 + 2 * j_)) * 512 + sc;
        m_ = m0 + 64 + sr; if (m_ > M - 1) m_ = M - 1;
        b_ = m_ / 196; rem = m_ - b_ * 196; i_ = rem / 14; j_ = rem - i_ * 14;
        aP1 = A + ((size_t)(b_ * 784 + 2 * i_ * 28 + 2 * j_)) * 512 + sc;
    }
    const _Float16* bP0 = W + (size_t)(n0 + sr) * K + sc;
    const _Float16* bP1 = W + (size_t)(n0 + 64 + sr) * K + sc;

    const int mw = wid & 1, nw = wid >> 1;
    const _Float16* pA = sA + (mw * 64 + (lane & 15)) * 32 + (lane >> 4) * 8;
    const _Float16* pB = sB + (nw * 64 + (lane & 15)) * 32 + (lane >> 4) * 8;

    f32x4 acc[4][4];
#pragma unroll
    for (int i = 0; i < 4; ++i)
#pragma unroll
        for (int j = 0; j < 4; ++j) acc[i][j] = (f32x4)(0.0f);

    for (int k0 = 0; k0 < K; k0 += 32) {
        int aOff;
        if constexpr (ALOAD == 0) {
            aOff = k0;
        } else if constexpr (ALOAD == 1) {
            int sub = k0 >> 9; int s3 = sub / 3;
            int dy = s3 - 1, dx = sub - s3 * 3 - 1;
            aOff = (dy * 30 + dx) * 512 + (k0 & 511);
        } else {
            int sub = k0 >> 9; int ky = sub >> 1, kx = sub & 1;
            aOff = (ky * 28 + kx) * 512 + (k0 & 511);
        }
        __syncthreads();   // prior iteration's ds_reads done before overwrite
        async_copy16(aP0 + aOff, ldsA0);
        async_copy16(aP1 + aOff, ldsA1);
        async_copy16(bP0 + k0, ldsB0);
        async_copy16(bP1 + k0, ldsB1);
        __syncthreads();   // vmcnt(0) drain -> staged data visible

        half8 aF[4], bF[4];
#pragma unroll
        for (int i = 0; i < 4; ++i) aF[i] = *(const half8*)(pA + i * 512);
#pragma unroll
        for (int j = 0; j < 4; ++j) bF[j] = *(const half8*)(pB + j * 512);
#pragma unroll
        for (int i = 0; i < 4; ++i)
#pragma unroll
            for (int j = 0; j < 4; ++j)
                acc[i][j] = __builtin_amdgcn_mfma_f32_16x16x32_f16(
                    aF[i], bF[j], acc[i][j], 0, 0, 0);
    }

    // epilogue: C/D layout col=lane&15, row=(lane>>4)*4+reg
    const int orow = m0 + mw * 64 + (lane >> 4) * 4;
    const int ocol = n0 + nw * 64 + (lane & 15);
#pragma unroll
    for (int j = 0; j < 4; ++j) {
        int col = ocol + j * 16;
        float bv = bias[col];
        float g = 0.0f, b2 = 0.0f;
        if constexpr (EPI == 1) { g = bng[col] * BN_RSQ; b2 = bnb[col]; }
#pragma unroll
        for (int i = 0; i < 4; ++i) {
#pragma unroll
            for (int r = 0; r < 4; ++r) {
                int row = orow + i * 16 + r;
                if (row >= M) continue;
                float v = acc[i][j][r] + bv;
                if constexpr (EPI == 1) v = fmaxf(v * g + b2, 0.0f);
                if constexpr (EPI == 0)
                    ((float*)outp)[(size_t)row * ldc + col] = v;
                else
                    ((_Float16*)outp)[(size_t)row * ldc + col] = (_Float16)v;
            }
        }
    }
}

// =====================================================================
// small utility kernels
// =====================================================================
__global__ __launch_bounds__(256) void cvt_f32_f16(
    const float* __restrict__ s, _Float16* __restrict__ d, int n8)
{
    int i = blockIdx.x * 256 + threadIdx.x;
    if (i >= n8) return;
    const float4* sp = (const float4*)(s + (size_t)i * 8);
    float4 a = sp[0], b = sp[1];
    half8 h;
    h[0] = (_Float16)a.x; h[1] = (_Float16)a.y; h[2] = (_Float16)a.z; h[3] = (_Float16)a.w;
    h[4] = (_Float16)b.x; h[5] = (_Float16)b.y; h[6] = (_Float16)b.z; h[7] = (_Float16)b.w;
    *(half8*)(d + (size_t)i * 8) = h;
}

__global__ __launch_bounds__(256) void zero_half(_Float16* __restrict__ p, int n8)
{
    int i = blockIdx.x * 256 + threadIdx.x;
    if (i < n8) *(float4*)(p + (size_t)i * 8) = make_float4(0.f, 0.f, 0.f, 0.f);
}

__global__ __launch_bounds__(256) void transpose_filter16(
    const float* __restrict__ fw, _Float16* __restrict__ wT)
{   // wT[n][(ky*3+kx)*512 + ci] = fw[n][ci][ky][kx]; 512*4608
    int idx = blockIdx.x * 256 + threadIdx.x;
    int n = idx / 4608; int r = idx - n * 4608;
    int sub = r >> 9; int ci = r & 511;
    wT[idx] = (_Float16)fw[(size_t)n * 4608 + ci * 9 + sub];
}

__global__ __launch_bounds__(256) void transpose_kve16(
    const float* __restrict__ kw, _Float16* __restrict__ kT)
{   // kT[n][(ky*2+kx)*512 + ci] = kw[n][ci][ky][kx]; 512*2048
    int idx = blockIdx.x * 256 + threadIdx.x;
    int n = idx >> 11; int r = idx & 2047;
    int sub = r >> 9; int ci = r & 511;
    kT[idx] = (_Float16)kw[((size_t)n << 11) + (ci << 2) + sub];
}

// V^T prep: vt[((b*8+h)*64+d)*224 + m] = kv[b][m][512 + h*64 + d], 0 for m>=196
__global__ __launch_bounds__(256) void vt_prep(
    const _Float16* __restrict__ kv, _Float16* __restrict__ vt)
{
    int idx = blockIdx.x * 256 + threadIdx.x;   // 917504 total
    int m = idx % 224;
    int rest = idx / 224;
    int d = rest & 63;
    int bh = rest >> 6;
    int b = bh >> 3, h = bh & 7;
    _Float16 v = (_Float16)0.0f;
    if (m < 196)
        v = kv[((size_t)(b * 196 + m)) * 1024 + 512 + h * 64 + d];
    vt[idx] = v;
}

// =====================================================================
// Haar DWT: rbuf16 (B,56,56,128 NHWC fp16) -> padded (B,30,30,512 NHWC fp16)
// =====================================================================
__global__ __launch_bounds__(128) void dwt_kernel(
    const _Float16* __restrict__ r, _Float16* __restrict__ pad)
{
    int bid = blockIdx.x;            // b*784 + i*28 + j
    int b = bid / 784; int rem = bid - b * 784;
    int i = rem / 28;  int j = rem - i * 28;
    int c = threadIdx.x;
    int y = 2 * i, x = 2 * j;
    size_t base = (size_t)b * 3136;
    _Float16 f1 = r[(base + (size_t)y * 56 + x) * 128 + c];
    _Float16 f2 = r[(base + (size_t)(y + 1) * 56 + x) * 128 + c];
    _Float16 f3 = r[(base + (size_t)y * 56 + (x + 1)) * 128 + c];
    _Float16 f4 = r[(base + (size_t)(y + 1) * 56 + (x + 1)) * 128 + c];
    _Float16 h = (_Float16)0.5f;
    _Float16 x1 = f1 * h, x2 = f2 * h, x3 = f3 * h, x4 = f4 * h;
    _Float16 ll = ((x1 + x2) + x3) + x4;
    _Float16 hl = (((-x1) - x2) + x3) + x4;
    _Float16 lh = (((-x1) + x2) - x3) + x4;
    _Float16 hh = ((x1 - x2) - x3) + x4;
    size_t ob = ((size_t)b * 900 + (size_t)(i + 1) * 30 + (j + 1)) * 512;
    pad[ob + c]       = ll;
    pad[ob + 128 + c] = hl;
    pad[ob + 256 + c] = lh;
    pad[ob + 384 + c] = hh;
}

// =====================================================================
// Haar IDWT: dwt_b16 (B,28,28,512 NHWC fp16) -> cat16 cols 512..639
// =====================================================================
__global__ __launch_bounds__(128) void idwt_kernel(
    const _Float16* __restrict__ d, _Float16* __restrict__ cat)
{
    int bid = blockIdx.x;
    int b = bid / 784; int rem = bid - b * 784;
    int i = rem / 28;  int j = rem - i * 28;
    int c = threadIdx.x;
    size_t ib = ((size_t)b * 784 + (size_t)i * 28 + j) * 512;
    _Float16 ll = d[ib + c];
    _Float16 hl = d[ib + 128 + c];
    _Float16 lh = d[ib + 256 + c];
    _Float16 hh = d[ib + 384 + c];
    _Float16 h = (_Float16)0.5f;
    _Float16 p1 = (((ll - hl) - lh) + hh) * h;
    _Float16 p2 = (((ll - hl) + lh) - hh) * h;
    _Float16 p3 = (((ll + hl) - lh) - hh) * h;
    _Float16 p4 = (((ll + hl) + lh) + hh) * h;
    int y = 2 * i, x = 2 * j;
    size_t rb = (size_t)b * 3136;
    cat[(rb + (size_t)y * 56 + x) * 640 + 512 + c]           = p1;
    cat[(rb + (size_t)y * 56 + x + 1) * 640 + 512 + c]       = p3;
    cat[(rb + (size_t)(y + 1) * 56 + x) * 640 + 512 + c]     = p2;
    cat[(rb + (size_t)(y + 1) * 56 + x + 1) * 640 + 512 + c] = p4;
}

// =====================================================================
// LayerNorm over C=512 (fp32 in, fp16 out), one wave per row
// =====================================================================
__global__ __launch_bounds__(256) void ln_kernel(
    const float* __restrict__ p, _Float16* __restrict__ o,
    const float* __restrict__ g, const float* __restrict__ bta)
{
    int wave = threadIdx.x >> 6;
    int lane = threadIdx.x & 63;
    int row = blockIdx.x * 4 + wave;            // 392*4 = 1568
    const float* rp = p + (size_t)row * 512;
    float v[8];
    *(float4*)&v[0] = *(const float4*)(rp + lane * 8);
    *(float4*)&v[4] = *(const float4*)(rp + lane * 8 + 4);
    float s = ((v[0] + v[1]) + (v[2] + v[3])) + ((v[4] + v[5]) + (v[6] + v[7]));
#pragma unroll
    for (int off = 32; off; off >>= 1) s += __shfl_xor(s, off);
    float mu = s * (1.0f / 512.0f);
    float sq = 0.0f;
#pragma unroll
    for (int i = 0; i < 8; ++i) { v[i] -= mu; sq += v[i] * v[i]; }
#pragma unroll
    for (int off = 32; off; off >>= 1) sq += __shfl_xor(sq, off);
    float inv = 1.0f / sqrtf(sq * (1.0f / 512.0f) + 1e-5f);
    int c = lane * 8;
    half8 hv;
#pragma unroll
    for (int i = 0; i < 8; ++i) hv[i] = (_Float16)(v[i] * inv * g[c + i] + bta[c + i]);
    *(half8*)(o + (size_t)row * 512 + c) = hv;
}

// =====================================================================
// MFMA flash attention. Block = (b, h, 64 q-rows); 4 waves x 16 q-rows.
// Scores are tiny (|s*scale| < ~4) so softmax uses NO max subtraction:
// unnormalized p = exp2(s*scale*log2e), row-sum reduced once at the end.
// K staged per 64-m chunk from kv; V^T staged from pre-transposed vt.
// P goes C-layout -> LDS(fp16) -> A-layout (m120 pattern), wave-private.
// =====================================================================
__global__ __launch_bounds__(256) void attn_mfma(
    const _Float16* __restrict__ q, const _Float16* __restrict__ kv,
    const _Float16* __restrict__ vt, _Float16* __restrict__ cat)
{
    __shared__ _Float16 sK[64][72];    // K[m][d],  rows padded: 16B-aligned, 2-way banks
    __shared__ _Float16 sVT[64][72];   // V^T[d][m-chunk]
    __shared__ _Float16 sP[4][16][40]; // per-wave P round-trip
    int bid = blockIdx.x;
    int qt = bid % 49;
    int h  = (bid / 49) & 7;
    int b  = bid / 392;
    int n0 = qt * 64;
    int t = threadIdx.x, lane = t & 63, wid = t >> 6;
    int quad = lane >> 4, l16 = lane & 15;

    // Q A-fragments (wave owns q rows n0 + wid*16 .. +15), straight from global
    const _Float16* qp = q + ((size_t)(b * 3136 + n0 + wid * 16 + l16)) * 512
                           + h * 64 + quad * 8;
    half8 aQ0 = *(const half8*)qp;          // d = quad*8 + 0..7   (k 0..31)
    half8 aQ1 = *(const half8*)(qp + 32);   // d = 32 + quad*8 + j (k 32..63)

    f32x4 oacc[4];
#pragma unroll
    for (int i = 0; i < 4; ++i) oacc[i] = (f32x4)(0.0f);
    float lsum[4] = {0.f, 0.f, 0.f, 0.f};

    const _Float16* vtb = vt + ((size_t)((b * 8 + h) * 64)) * 224;

    for (int c0 = 0; c0 < 224; c0 += 64) {
        __syncthreads();   // previous chunk's frag reads done
#pragma unroll
        for (int it = 0; it < 2; ++it) {   // stage sK: 512 slots of 16B
            int slot = t + 256 * it;
            int row = slot >> 3, c8 = (slot & 7) * 8;
            int m = c0 + row; if (m > 195) m = 195;   // garbage rows masked later
            *(half8*)&sK[row][c8] =
                *(const half8*)(kv + ((size_t)(b * 196 + m)) * 1024 + h * 64 + c8);
        }
#pragma unroll
        for (int it = 0; it < 2; ++it) {   // stage sVT: 512 slots of 16B
            int slot = t + 256 * it;
            int row = slot >> 3, c8 = (slot & 7) * 8;
            *(half8*)&sVT[row][c8] =
                *(const half8*)(vtb + (size_t)row * 224 + c0 + c8);
        }
        __syncthreads();

#pragma unroll
        for (int sc = 0; sc < 64; sc += 32) {
            // K B-fragments: two 16-m tiles x two 32-d halves
            half8 bk00 = *(const half8*)&sK[sc + l16][quad * 8];
            half8 bk01 = *(const half8*)&sK[sc + l16][32 + quad * 8];
            half8 bk10 = *(const half8*)&sK[sc + 16 + l16][quad * 8];
            half8 bk11 = *(const half8*)&sK[sc + 16 + l16][32 + quad * 8];
            f32x4 s0 = (f32x4)(0.0f), s1 = (f32x4)(0.0f);
            s0 = __builtin_amdgcn_mfma_f32_16x16x32_f16(aQ0, bk00, s0, 0, 0, 0);
            s0 = __builtin_amdgcn_mfma_f32_16x16x32_f16(aQ1, bk01, s0, 0, 0, 0);
            s1 = __builtin_amdgcn_mfma_f32_16x16x32_f16(aQ0, bk10, s1, 0, 0, 0);
            s1 = __builtin_amdgcn_mfma_f32_16x16x32_f16(aQ1, bk11, s1, 0, 0, 0);

            int col0 = c0 + sc + l16;
            float msk0 = (col0 < 196) ? 0.0f : -INFINITY;
            float msk1 = (col0 + 16 < 196) ? 0.0f : -INFINITY;
            float p0[4], p1[4];
#pragma unroll
            for (int r = 0; r < 4; ++r) {
                p0[r] = exp2f(s0[r] * SCL2 + msk0);
                p1[r] = exp2f(s1[r] * SCL2 + msk1);
                lsum[r] += p0[r] + p1[r];
            }
            // P: C-layout -> wave-private LDS -> A-layout (in-order DS per wave)
#pragma unroll
            for (int r = 0; r < 4; ++r) {
                sP[wid][quad * 4 + r][l16]      = (_Float16)p0[r];
                sP[wid][quad * 4 + r][16 + l16] = (_Float16)p1[r];
            }
            half8 aP = *(const half8*)&sP[wid][l16][quad * 8];
            half8 bv0 = *(const half8*)&sVT[l16][sc + quad * 8];
            half8 bv1 = *(const half8*)&sVT[16 + l16][sc + quad * 8];
            half8 bv2 = *(const half8*)&sVT[32 + l16][sc + quad * 8];
            half8 bv3 = *(const half8*)&sVT[48 + l16][sc + quad * 8];
            oacc[0] = __builtin_amdgcn_mfma_f32_16x16x32_f16(aP, bv0, oacc[0], 0, 0, 0);
            oacc[1] = __builtin_amdgcn_mfma_f32_16x16x32_f16(aP, bv1, oacc[1], 0, 0, 0);
            oacc[2] = __builtin_amdgcn_mfma_f32_16x16x32_f16(aP, bv2, oacc[2], 0, 0, 0);
            oacc[3] = __builtin_amdgcn_mfma_f32_16x16x32_f16(aP, bv3, oacc[3], 0, 0, 0);
        }
    }

    // single row-sum reduction (16 lanes per row group share quad)
    float inv[4];
#pragma unroll
    for (int r = 0; r < 4; ++r) {
        float s = lsum[r];
        s += __shfl_xor(s, 1);
        s += __shfl_xor(s, 2);
        s += __shfl_xor(s, 4);
        s += __shfl_xor(s, 8);
        inv[r] = 1.0f / s;
    }
    // epilogue: row = n0 + wid*16 + quad*4 + r, col d = tv*16 + l16
#pragma unroll
    for (int r = 0; r < 4; ++r) {
        size_t rowoff = ((size_t)(b * 3136 + n0 + wid * 16 + quad * 4 + r)) * 640
                        + h * 64 + l16;
#pragma unroll
        for (int tv = 0; tv < 4; ++tv)
            cat[rowoff + tv * 16] = (_Float16)(oacc[tv][r] * inv[r]);
    }
}

// =====================================================================
extern "C" void kernel_launch(void* const* d_in, const int* in_sizes, int n_in,
                              void* d_out, int out_size, void* d_ws, size_t ws_size,
                              hipStream_t stream)
{
    const float* x           = (const float*)d_in[0];
    const float* reduce_w    = (const float*)d_in[3];
    const float* reduce_b    = (const float*)d_in[4];
    const float* reduce_g    = (const float*)d_in[5];
    const float* reduce_beta = (const float*)d_in[6];
    const float* filter_w    = (const float*)d_in[7];
    const float* filter_b    = (const float*)d_in[8];
    const float* filter_g    = (const float*)d_in[9];
    const float* filter_beta = (const float*)d_in[10];
    const float* q_w         = (const float*)d_in[11];
    const float* q_b         = (const float*)d_in[12];
    const float* ln_g        = (const float*)d_in[13];
    const float* ln_b        = (const float*)d_in[14];
    const float* kv_w        = (const float*)d_in[15];
    const float* kv_b        = (const float*)d_in[16];
    const float* kve_w       = (const float*)d_in[17];
    const float* kve_b       = (const float*)d_in[18];
    const float* proj_w      = (const float*)d_in[19];
    const float* proj_b      = (const float*)d_in[20];
    float* out = (float*)d_out;
    _Float16* hws = (_Float16*)d_ws;

    _Float16* x16    = hws + OFF_X16;
    _Float16* q16    = hws + OFF_Q16;
    _Float16* cat16  = hws + OFF_CAT;
    _Float16* r16    = hws + OFF_R16;
    _Float16* pad16  = hws + OFF_PAD;
    _Float16* dwtb16 = hws + OFF_DWTB;
    float*    kv_in  = (float*)(hws + OFF_KVIN);
    _Float16* ln16   = hws + OFF_LN16;
    _Float16* kv16   = hws + OFF_KV16;
    _Float16* wT16   = hws + OFF_WT;
    _Float16* kT16   = hws + OFF_KT;
    _Float16* qw16   = hws + OFF_QW;
    _Float16* kvw16  = hws + OFF_KVW;
    _Float16* pw16   = hws + OFF_PW;
    _Float16* rw16   = hws + OFF_RW;
    _Float16* vt16   = hws + OFF_VT;

    // conversions / transposes / padding init
    cvt_f32_f16<<<dim3(6272), dim3(256), 0, stream>>>(x, x16, 1605632);
    cvt_f32_f16<<<dim3(128),  dim3(256), 0, stream>>>(q_w, qw16, 32768);
    cvt_f32_f16<<<dim3(256),  dim3(256), 0, stream>>>(kv_w, kvw16, 65536);
    cvt_f32_f16<<<dim3(160),  dim3(256), 0, stream>>>(proj_w, pw16, 40960);
    cvt_f32_f16<<<dim3(32),   dim3(256), 0, stream>>>(reduce_w, rw16, 8192);
    transpose_filter16<<<dim3(9216), dim3(256), 0, stream>>>(filter_w, wT16);
    transpose_kve16<<<dim3(4096), dim3(256), 0, stream>>>(kve_w, kT16);
    zero_half<<<dim3(1800), dim3(256), 0, stream>>>(pad16, 460800);

    // q = x @ q_w.T + q_b  -> fp16
    gemm16<0, 2><<<dim3(196, 4), dim3(256), 0, stream>>>(
        x16, qw16, q16, 25088, 512, 512, 512, q_b, nullptr, nullptr);

    // r = fp16(relu(bn(conv1x1(x))))  (25088 x 128 NHWC fp16)
    gemm16<0, 1><<<dim3(196, 1), dim3(256), 0, stream>>>(
        x16, rw16, r16, 25088, 512, 512, 128, reduce_b, reduce_g, reduce_beta);

    // DWT -> padded 30x30x512
    dwt_kernel<<<dim3(6272), dim3(128), 0, stream>>>(r16, pad16);

    // 3x3 conv + bn + relu + fp16 -> dwt_b
    gemm16<1, 1><<<dim3(49, 4), dim3(256), 0, stream>>>(
        pad16, wT16, dwtb16, 6272, 4608, 0, 512, filter_b, filter_g, filter_beta);

    // IDWT -> cat cols 512..639
    idwt_kernel<<<dim3(6272), dim3(128), 0, stream>>>(dwtb16, cat16);

    // kve 2x2 s2 conv -> kv_in (fp32)
    gemm16<2, 0><<<dim3(13, 4), dim3(256), 0, stream>>>(
        dwtb16, kT16, kv_in, 1568, 2048, 0, 512, kve_b, nullptr, nullptr);

    // LayerNorm -> fp16
    ln_kernel<<<dim3(392), dim3(256), 0, stream>>>(kv_in, ln16, ln_g, ln_b);

    // kv = ln @ kv_w.T + kv_b -> fp16 (1568 x 1024)
    gemm16<0, 2><<<dim3(13, 8), dim3(256), 0, stream>>>(
        ln16, kvw16, kv16, 1568, 512, 512, 1024, kv_b, nullptr, nullptr);

    // V^T for attention B-operand
    vt_prep<<<dim3(3584), dim3(256), 0, stream>>>(kv16, vt16);

    // attention -> cat cols 0..511
    attn_mfma<<<dim3(3136), dim3(256), 0, stream>>>(q16, kv16, vt16, cat16);

    // out = cat @ proj_w.T + proj_b  (fp32)
    gemm16<0, 0><<<dim3(196, 4), dim3(256), 0, stream>>>(
        cat16, pw16, out, 25088, 640, 640, 512, proj_b, nullptr, nullptr);
}

// Round 5
// 487.519 us; speedup vs baseline: 4.0513x; 1.0926x over previous
//
#include <hip/hip_runtime.h>
#include <math.h>

// Problem constants: B=8, H=W=56, C=512, N=3136, c4=128, HEADS=8, hd=64, SR=2
// kv sequence length = 14*14 = 196 (padded to 224 for attention)

typedef _Float16 half8 __attribute__((ext_vector_type(8)));
typedef _Float16 half4v __attribute__((ext_vector_type(4)));
typedef float f32x4 __attribute__((ext_vector_type(4)));

// ---------------- workspace layout (offsets in halves; all 16B-aligned) ----
static const size_t OFF_X16  = 0;          // 25088*512 (dead after q/r gemms; reused as conv partials 0,1)
static const size_t OFF_Q16  = 12845056;   // 25088*512
static const size_t OFF_CAT  = 25690112;   // 25088*640
static const size_t OFF_R16  = 41746432;   // 25088*128
static const size_t OFF_PAD  = 44957696;   // 8*900*512  (30x30 zero-padded DWT)
static const size_t OFF_DWTB = 48644096;   // 8*784*512
static const size_t OFF_KVIN = 51855360;   // 1568*512 floats = 3,211,264 halves
static const size_t OFF_LN16 = 55066624;   // 1568*512
static const size_t OFF_KV16 = 55869440;   // 1568*1024
static const size_t OFF_WT   = 57475072;   // 512*4608
static const size_t OFF_KT   = 59834368;   // 512*2048
static const size_t OFF_QW   = 60882944;   // 512*512
static const size_t OFF_KVW  = 61145088;   // 1024*512
static const size_t OFF_PW   = 61669376;   // 512*640
static const size_t OFF_RW   = 61997056;   // 128*512
static const size_t OFF_VT   = 62062592;   // 8*8*64*224 = 917504 (V^T, m-padded)
static const size_t OFF_PART = 62980096;   // conv partials 2,3: 2*3,211,264 floats
// total = 75,825,152 halves = 151.7 MB (<= 153.9 MB proven available in R1)

#define BN_RSQ 0.9999950000374997f
#define SCL2   0.1803368801111204f   /* 0.125 * log2(e) */
#define PART_STRIDE 3211264          /* 6272*512 floats per conv partial */

__device__ __forceinline__ void async_copy16(const _Float16* g, _Float16* l) {
    __builtin_amdgcn_global_load_lds(
        (const __attribute__((address_space(1))) void*)g,
        (__attribute__((address_space(3))) void*)l, 16, 0, 0);
}

// =====================================================================
// MFMA fp16 NT GEMM: out[m][n] = sum_k A[m][k]*W[n][k] (+ epilogue)
// ALOAD: 0 plain row-major (lda), 2 kve 2x2 stride-2 on 28x28x512 NHWC
// EPI:   0 = +bias -> fp32, 1 = +bias,BN,ReLU -> fp16, 2 = +bias -> fp16
// 128x128 tile, BK=32, 256 threads (4 waves 2x2), 16x16x32 MFMA.
// =====================================================================
template <int ALOAD, int EPI>
__global__ __launch_bounds__(256) void gemm16(
    const _Float16* __restrict__ A, const _Float16* __restrict__ W,
    void* __restrict__ outp, int M, int K, int lda, int ldc,
    const float* __restrict__ bias, const float* __restrict__ bng,
    const float* __restrict__ bnb)
{
    __shared__ _Float16 sA[128 * 32];
    __shared__ _Float16 sB[128 * 32];
    const int t = threadIdx.x;
    const int lane = t & 63, wid = t >> 6;
    const int m0 = blockIdx.x * 128, n0 = blockIdx.y * 128;

    const int sr = wid * 16 + (lane >> 2);   // staging tile row (instr0)
    const int sc = (lane & 3) * 8;           // staging col offset (halves)
    _Float16* ldsA0 = sA + wid * 512;
    _Float16* ldsA1 = sA + 2048 + wid * 512;
    _Float16* ldsB0 = sB + wid * 512;
    _Float16* ldsB1 = sB + 2048 + wid * 512;

    const _Float16 *aP0, *aP1;
    if constexpr (ALOAD == 0) {
        int r0 = m0 + sr;      if (r0 > M - 1) r0 = M - 1;
        int r1 = m0 + 64 + sr; if (r1 > M - 1) r1 = M - 1;
        aP0 = A + (size_t)r0 * lda + sc;
        aP1 = A + (size_t)r1 * lda + sc;
    } else {
        int m_ = m0 + sr; if (m_ > M - 1) m_ = M - 1;
        int b_ = m_ / 196, rem = m_ - b_ * 196, i_ = rem / 14, j_ = rem - i_ * 14;
        aP0 = A + ((size_t)(b_ * 784 + 2 * i_ * 28 + 2 * j_)) * 512 + sc;
        m_ = m0 + 64 + sr; if (m_ > M - 1) m_ = M - 1;
        b_ = m_ / 196; rem = m_ - b_ * 196; i_ = rem / 14; j_ = rem - i_ * 14;
        aP1 = A + ((size_t)(b_ * 784 + 2 * i_ * 28 + 2 * j_)) * 512 + sc;
    }
    const _Float16* bP0 = W + (size_t)(n0 + sr) * K + sc;
    const _Float16* bP1 = W + (size_t)(n0 + 64 + sr) * K + sc;

    const int mw = wid & 1, nw = wid >> 1;
    const _Float16* pA = sA + (mw * 64 + (lane & 15)) * 32 + (lane >> 4) * 8;
    const _Float16* pB = sB + (nw * 64 + (lane & 15)) * 32 + (lane >> 4) * 8;

    f32x4 acc[4][4];
#pragma unroll
    for (int i = 0; i < 4; ++i)
#pragma unroll
        for (int j = 0; j < 4; ++j) acc[i][j] = (f32x4)(0.0f);

    for (int k0 = 0; k0 < K; k0 += 32) {
        int aOff;
        if constexpr (ALOAD == 0) {
            aOff = k0;
        } else {
            int sub = k0 >> 9; int ky = sub >> 1, kx = sub & 1;
            aOff = (ky * 28 + kx) * 512 + (k0 & 511);
        }
        __syncthreads();   // prior iteration's ds_reads done before overwrite
        async_copy16(aP0 + aOff, ldsA0);
        async_copy16(aP1 + aOff, ldsA1);
        async_copy16(bP0 + k0, ldsB0);
        async_copy16(bP1 + k0, ldsB1);
        __syncthreads();   // vmcnt(0) drain -> staged data visible

        half8 aF[4], bF[4];
#pragma unroll
        for (int i = 0; i < 4; ++i) aF[i] = *(const half8*)(pA + i * 512);
#pragma unroll
        for (int j = 0; j < 4; ++j) bF[j] = *(const half8*)(pB + j * 512);
#pragma unroll
        for (int i = 0; i < 4; ++i)
#pragma unroll
            for (int j = 0; j < 4; ++j)
                acc[i][j] = __builtin_amdgcn_mfma_f32_16x16x32_f16(
                    aF[i], bF[j], acc[i][j], 0, 0, 0);
    }

    // epilogue: C/D layout col=lane&15, row=(lane>>4)*4+reg
    const int orow = m0 + mw * 64 + (lane >> 4) * 4;
    const int ocol = n0 + nw * 64 + (lane & 15);
#pragma unroll
    for (int j = 0; j < 4; ++j) {
        int col = ocol + j * 16;
        float bv = bias[col];
        float g = 0.0f, b2 = 0.0f;
        if constexpr (EPI == 1) { g = bng[col] * BN_RSQ; b2 = bnb[col]; }
#pragma unroll
        for (int i = 0; i < 4; ++i) {
#pragma unroll
            for (int r = 0; r < 4; ++r) {
                int row = orow + i * 16 + r;
                if (row >= M) continue;
                float v = acc[i][j][r] + bv;
                if constexpr (EPI == 1) v = fmaxf(v * g + b2, 0.0f);
                if constexpr (EPI == 0)
                    ((float*)outp)[(size_t)row * ldc + col] = v;
                else
                    ((_Float16*)outp)[(size_t)row * ldc + col] = (_Float16)v;
            }
        }
    }
}

// =====================================================================
// conv3x3 split-K partial GEMM: grid (49, 4, 4); K-group bz covers
// k in [bz*1152, (bz+1)*1152). Writes fp32 partial (no bias).
// A = padded 30x30x512 NHWC fp16; W = wT[n][(ky*3+kx)*512+ci].
// =====================================================================
__global__ __launch_bounds__(256) void conv_splitk(
    const _Float16* __restrict__ A, const _Float16* __restrict__ W,
    float* __restrict__ partA, float* __restrict__ partB)
{
    __shared__ _Float16 sA[128 * 32];
    __shared__ _Float16 sB[128 * 32];
    const int t = threadIdx.x;
    const int lane = t & 63, wid = t >> 6;
    const int m0 = blockIdx.x * 128, n0 = blockIdx.y * 128;
    const int kbase = blockIdx.z * 1152;

    const int sr = wid * 16 + (lane >> 2);
    const int sc = (lane & 3) * 8;
    _Float16* ldsA0 = sA + wid * 512;
    _Float16* ldsA1 = sA + 2048 + wid * 512;
    _Float16* ldsB0 = sB + wid * 512;
    _Float16* ldsB1 = sB + 2048 + wid * 512;

    int m_ = m0 + sr;
    int b_ = m_ / 784, rem = m_ - b_ * 784, y_ = rem / 28, x_ = rem - y_ * 28;
    const _Float16* aP0 = A + ((size_t)(b_ * 900 + (y_ + 1) * 30 + (x_ + 1))) * 512 + sc;
    m_ = m0 + 64 + sr;
    b_ = m_ / 784; rem = m_ - b_ * 784; y_ = rem / 28; x_ = rem - y_ * 28;
    const _Float16* aP1 = A + ((size_t)(b_ * 900 + (y_ + 1) * 30 + (x_ + 1))) * 512 + sc;
    const _Float16* bP0 = W + (size_t)(n0 + sr) * 4608 + sc;
    const _Float16* bP1 = W + (size_t)(n0 + 64 + sr) * 4608 + sc;

    const int mw = wid & 1, nw = wid >> 1;
    const _Float16* pA = sA + (mw * 64 + (lane & 15)) * 32 + (lane >> 4) * 8;
    const _Float16* pB = sB + (nw * 64 + (lane & 15)) * 32 + (lane >> 4) * 8;

    f32x4 acc[4][4];
#pragma unroll
    for (int i = 0; i < 4; ++i)
#pragma unroll
        for (int j = 0; j < 4; ++j) acc[i][j] = (f32x4)(0.0f);

    for (int k0 = kbase; k0 < kbase + 1152; k0 += 32) {
        int sub = k0 >> 9; int s3 = sub / 3;
        int dy = s3 - 1, dx = sub - s3 * 3 - 1;
        int aOff = (dy * 30 + dx) * 512 + (k0 & 511);
        __syncthreads();
        async_copy16(aP0 + aOff, ldsA0);
        async_copy16(aP1 + aOff, ldsA1);
        async_copy16(bP0 + k0, ldsB0);
        async_copy16(bP1 + k0, ldsB1);
        __syncthreads();

        half8 aF[4], bF[4];
#pragma unroll
        for (int i = 0; i < 4; ++i) aF[i] = *(const half8*)(pA + i * 512);
#pragma unroll
        for (int j = 0; j < 4; ++j) bF[j] = *(const half8*)(pB + j * 512);
#pragma unroll
        for (int i = 0; i < 4; ++i)
#pragma unroll
            for (int j = 0; j < 4; ++j)
                acc[i][j] = __builtin_amdgcn_mfma_f32_16x16x32_f16(
                    aF[i], bF[j], acc[i][j], 0, 0, 0);
    }

    float* dst = (blockIdx.z < 2) ? (partA + (size_t)blockIdx.z * PART_STRIDE)
                                  : (partB + (size_t)(blockIdx.z - 2) * PART_STRIDE);
    const int orow = m0 + mw * 64 + (lane >> 4) * 4;
    const int ocol = n0 + nw * 64 + (lane & 15);
#pragma unroll
    for (int j = 0; j < 4; ++j) {
#pragma unroll
        for (int i = 0; i < 4; ++i)
#pragma unroll
            for (int r = 0; r < 4; ++r)
                dst[(size_t)(orow + i * 16 + r) * 512 + ocol + j * 16] = acc[i][j][r];
    }
}

// conv epilogue: dwtb16 = fp16(relu((p0+p1+p2+p3 + bias) * g*BN_RSQ + beta))
__global__ __launch_bounds__(256) void conv_epi(
    const float* __restrict__ pA, const float* __restrict__ pB,
    _Float16* __restrict__ o, const float* __restrict__ bias,
    const float* __restrict__ bng, const float* __restrict__ bnb)
{
    int i = blockIdx.x * 256 + threadIdx.x;      // 401,408 groups of 8
    size_t base = (size_t)i * 8;
    int c = (int)(base & 511);
    half8 hv;
#pragma unroll
    for (int u = 0; u < 8; u += 4) {
        float4 a0 = *(const float4*)(pA + base + u);
        float4 a1 = *(const float4*)(pA + PART_STRIDE + base + u);
        float4 a2 = *(const float4*)(pB + base + u);
        float4 a3 = *(const float4*)(pB + PART_STRIDE + base + u);
        float s[4] = {a0.x + a1.x + a2.x + a3.x, a0.y + a1.y + a2.y + a3.y,
                      a0.z + a1.z + a2.z + a3.z, a0.w + a1.w + a2.w + a3.w};
#pragma unroll
        for (int v = 0; v < 4; ++v) {
            int cc = c + u + v;
            float val = (s[v] + bias[cc]) * (bng[cc] * BN_RSQ) + bnb[cc];
            hv[u + v] = (_Float16)fmaxf(val, 0.0f);
        }
    }
    *(half8*)(o + base) = hv;
}

// =====================================================================
// small utility kernels
// =====================================================================
__global__ __launch_bounds__(256) void cvt_f32_f16(
    const float* __restrict__ s, _Float16* __restrict__ d, int n8)
{
    int i = blockIdx.x * 256 + threadIdx.x;
    if (i >= n8) return;
    const float4* sp = (const float4*)(s + (size_t)i * 8);
    float4 a = sp[0], b = sp[1];
    half8 h;
    h[0] = (_Float16)a.x; h[1] = (_Float16)a.y; h[2] = (_Float16)a.z; h[3] = (_Float16)a.w;
    h[4] = (_Float16)b.x; h[5] = (_Float16)b.y; h[6] = (_Float16)b.z; h[7] = (_Float16)b.w;
    *(half8*)(d + (size_t)i * 8) = h;
}

__global__ __launch_bounds__(256) void zero_half(_Float16* __restrict__ p, int n8)
{
    int i = blockIdx.x * 256 + threadIdx.x;
    if (i < n8) *(float4*)(p + (size_t)i * 8) = make_float4(0.f, 0.f, 0.f, 0.f);
}

__global__ __launch_bounds__(256) void transpose_filter16(
    const float* __restrict__ fw, _Float16* __restrict__ wT)
{   // wT[n][(ky*3+kx)*512 + ci] = fw[n][ci][ky][kx]; 512*4608
    int idx = blockIdx.x * 256 + threadIdx.x;
    int n = idx / 4608; int r = idx - n * 4608;
    int sub = r >> 9; int ci = r & 511;
    wT[idx] = (_Float16)fw[(size_t)n * 4608 + ci * 9 + sub];
}

__global__ __launch_bounds__(256) void transpose_kve16(
    const float* __restrict__ kw, _Float16* __restrict__ kT)
{   // kT[n][(ky*2+kx)*512 + ci] = kw[n][ci][ky][kx]; 512*2048
    int idx = blockIdx.x * 256 + threadIdx.x;
    int n = idx >> 11; int r = idx & 2047;
    int sub = r >> 9; int ci = r & 511;
    kT[idx] = (_Float16)kw[((size_t)n << 11) + (ci << 2) + sub];
}

// V^T prep: vt[((b*8+h)*64+d)*224 + m] = kv[b][m][512 + h*64 + d], 0 for m>=196
__global__ __launch_bounds__(256) void vt_prep(
    const _Float16* __restrict__ kv, _Float16* __restrict__ vt)
{
    int idx = blockIdx.x * 256 + threadIdx.x;   // 917504 total
    int m = idx % 224;
    int rest = idx / 224;
    int d = rest & 63;
    int bh = rest >> 6;
    int b = bh >> 3, h = bh & 7;
    _Float16 v = (_Float16)0.0f;
    if (m < 196)
        v = kv[((size_t)(b * 196 + m)) * 1024 + 512 + h * 64 + d];
    vt[idx] = v;
}

// =====================================================================
// Haar DWT: rbuf16 (B,56,56,128 NHWC fp16) -> padded (B,30,30,512 NHWC fp16)
// =====================================================================
__global__ __launch_bounds__(128) void dwt_kernel(
    const _Float16* __restrict__ r, _Float16* __restrict__ pad)
{
    int bid = blockIdx.x;            // b*784 + i*28 + j
    int b = bid / 784; int rem = bid - b * 784;
    int i = rem / 28;  int j = rem - i * 28;
    int c = threadIdx.x;
    int y = 2 * i, x = 2 * j;
    size_t base = (size_t)b * 3136;
    _Float16 f1 = r[(base + (size_t)y * 56 + x) * 128 + c];
    _Float16 f2 = r[(base + (size_t)(y + 1) * 56 + x) * 128 + c];
    _Float16 f3 = r[(base + (size_t)y * 56 + (x + 1)) * 128 + c];
    _Float16 f4 = r[(base + (size_t)(y + 1) * 56 + (x + 1)) * 128 + c];
    _Float16 h = (_Float16)0.5f;
    _Float16 x1 = f1 * h, x2 = f2 * h, x3 = f3 * h, x4 = f4 * h;
    _Float16 ll = ((x1 + x2) + x3) + x4;
    _Float16 hl = (((-x1) - x2) + x3) + x4;
    _Float16 lh = (((-x1) + x2) - x3) + x4;
    _Float16 hh = ((x1 - x2) - x3) + x4;
    size_t ob = ((size_t)b * 900 + (size_t)(i + 1) * 30 + (j + 1)) * 512;
    pad[ob + c]       = ll;
    pad[ob + 128 + c] = hl;
    pad[ob + 256 + c] = lh;
    pad[ob + 384 + c] = hh;
}

// =====================================================================
// Haar IDWT: dwt_b16 (B,28,28,512 NHWC fp16) -> cat16 cols 512..639
// =====================================================================
__global__ __launch_bounds__(128) void idwt_kernel(
    const _Float16* __restrict__ d, _Float16* __restrict__ cat)
{
    int bid = blockIdx.x;
    int b = bid / 784; int rem = bid - b * 784;
    int i = rem / 28;  int j = rem - i * 28;
    int c = threadIdx.x;
    size_t ib = ((size_t)b * 784 + (size_t)i * 28 + j) * 512;
    _Float16 ll = d[ib + c];
    _Float16 hl = d[ib + 128 + c];
    _Float16 lh = d[ib + 256 + c];
    _Float16 hh = d[ib + 384 + c];
    _Float16 h = (_Float16)0.5f;
    _Float16 p1 = (((ll - hl) - lh) + hh) * h;
    _Float16 p2 = (((ll - hl) + lh) - hh) * h;
    _Float16 p3 = (((ll + hl) - lh) - hh) * h;
    _Float16 p4 = (((ll + hl) + lh) + hh) * h;
    int y = 2 * i, x = 2 * j;
    size_t rb = (size_t)b * 3136;
    cat[(rb + (size_t)y * 56 + x) * 640 + 512 + c]           = p1;
    cat[(rb + (size_t)y * 56 + x + 1) * 640 + 512 + c]       = p3;
    cat[(rb + (size_t)(y + 1) * 56 + x) * 640 + 512 + c]     = p2;
    cat[(rb + (size_t)(y + 1) * 56 + x + 1) * 640 + 512 + c] = p4;
}

// =====================================================================
// LayerNorm over C=512 (fp32 in, fp16 out), one wave per row
// =====================================================================
__global__ __launch_bounds__(256) void ln_kernel(
    const float* __restrict__ p, _Float16* __restrict__ o,
    const float* __restrict__ g, const float* __restrict__ bta)
{
    int wave = threadIdx.x >> 6;
    int lane = threadIdx.x & 63;
    int row = blockIdx.x * 4 + wave;            // 392*4 = 1568
    const float* rp = p + (size_t)row * 512;
    float v[8];
    *(float4*)&v[0] = *(const float4*)(rp + lane * 8);
    *(float4*)&v[4] = *(const float4*)(rp + lane * 8 + 4);
    float s = ((v[0] + v[1]) + (v[2] + v[3])) + ((v[4] + v[5]) + (v[6] + v[7]));
#pragma unroll
    for (int off = 32; off; off >>= 1) s += __shfl_xor(s, off);
    float mu = s * (1.0f / 512.0f);
    float sq = 0.0f;
#pragma unroll
    for (int i = 0; i < 8; ++i) { v[i] -= mu; sq += v[i] * v[i]; }
#pragma unroll
    for (int off = 32; off; off >>= 1) sq += __shfl_xor(sq, off);
    float inv = 1.0f / sqrtf(sq * (1.0f / 512.0f) + 1e-5f);
    int c = lane * 8;
    half8 hv;
#pragma unroll
    for (int i = 0; i < 8; ++i) hv[i] = (_Float16)(v[i] * inv * g[c + i] + bta[c + i]);
    *(half8*)(o + (size_t)row * 512 + c) = hv;
}

// =====================================================================
// MFMA flash attention. Block = (b, h, 64 q-rows); 4 waves x 16 q-rows.
// Unnormalized softmax (scores tiny), one reduction at the end.
// =====================================================================
__global__ __launch_bounds__(256) void attn_mfma(
    const _Float16* __restrict__ q, const _Float16* __restrict__ kv,
    const _Float16* __restrict__ vt, _Float16* __restrict__ cat)
{
    __shared__ _Float16 sK[64][72];    // K[m][d]
    __shared__ _Float16 sVT[64][72];   // V^T[d][m-chunk]
    __shared__ _Float16 sP[4][16][40]; // per-wave P round-trip
    int bid = blockIdx.x;
    int qt = bid % 49;
    int h  = (bid / 49) & 7;
    int b  = bid / 392;
    int n0 = qt * 64;
    int t = threadIdx.x, lane = t & 63, wid = t >> 6;
    int quad = lane >> 4, l16 = lane & 15;

    const _Float16* qp = q + ((size_t)(b * 3136 + n0 + wid * 16 + l16)) * 512
                           + h * 64 + quad * 8;
    half8 aQ0 = *(const half8*)qp;
    half8 aQ1 = *(const half8*)(qp + 32);

    f32x4 oacc[4];
#pragma unroll
    for (int i = 0; i < 4; ++i) oacc[i] = (f32x4)(0.0f);
    float lsum[4] = {0.f, 0.f, 0.f, 0.f};

    const _Float16* vtb = vt + ((size_t)((b * 8 + h) * 64)) * 224;

    for (int c0 = 0; c0 < 224; c0 += 64) {
        __syncthreads();
#pragma unroll
        for (int it = 0; it < 2; ++it) {
            int slot = t + 256 * it;
            int row = slot >> 3, c8 = (slot & 7) * 8;
            int m = c0 + row; if (m > 195) m = 195;
            *(half8*)&sK[row][c8] =
                *(const half8*)(kv + ((size_t)(b * 196 + m)) * 1024 + h * 64 + c8);
        }
#pragma unroll
        for (int it = 0; it < 2; ++it) {
            int slot = t + 256 * it;
            int row = slot >> 3, c8 = (slot & 7) * 8;
            *(half8*)&sVT[row][c8] =
                *(const half8*)(vtb + (size_t)row * 224 + c0 + c8);
        }
        __syncthreads();

#pragma unroll
        for (int sc = 0; sc < 64; sc += 32) {
            half8 bk00 = *(const half8*)&sK[sc + l16][quad * 8];
            half8 bk01 = *(const half8*)&sK[sc + l16][32 + quad * 8];
            half8 bk10 = *(const half8*)&sK[sc + 16 + l16][quad * 8];
            half8 bk11 = *(const half8*)&sK[sc + 16 + l16][32 + quad * 8];
            f32x4 s0 = (f32x4)(0.0f), s1 = (f32x4)(0.0f);
            s0 = __builtin_amdgcn_mfma_f32_16x16x32_f16(aQ0, bk00, s0, 0, 0, 0);
            s0 = __builtin_amdgcn_mfma_f32_16x16x32_f16(aQ1, bk01, s0, 0, 0, 0);
            s1 = __builtin_amdgcn_mfma_f32_16x16x32_f16(aQ0, bk10, s1, 0, 0, 0);
            s1 = __builtin_amdgcn_mfma_f32_16x16x32_f16(aQ1, bk11, s1, 0, 0, 0);

            int col0 = c0 + sc + l16;
            float msk0 = (col0 < 196) ? 0.0f : -INFINITY;
            float msk1 = (col0 + 16 < 196) ? 0.0f : -INFINITY;
            float p0[4], p1[4];
#pragma unroll
            for (int r = 0; r < 4; ++r) {
                p0[r] = exp2f(s0[r] * SCL2 + msk0);
                p1[r] = exp2f(s1[r] * SCL2 + msk1);
                lsum[r] += p0[r] + p1[r];
            }
#pragma unroll
            for (int r = 0; r < 4; ++r) {
                sP[wid][quad * 4 + r][l16]      = (_Float16)p0[r];
                sP[wid][quad * 4 + r][16 + l16] = (_Float16)p1[r];
            }
            half8 aP = *(const half8*)&sP[wid][l16][quad * 8];
            half8 bv0 = *(const half8*)&sVT[l16][sc + quad * 8];
            half8 bv1 = *(const half8*)&sVT[16 + l16][sc + quad * 8];
            half8 bv2 = *(const half8*)&sVT[32 + l16][sc + quad * 8];
            half8 bv3 = *(const half8*)&sVT[48 + l16][sc + quad * 8];
            oacc[0] = __builtin_amdgcn_mfma_f32_16x16x32_f16(aP, bv0, oacc[0], 0, 0, 0);
            oacc[1] = __builtin_amdgcn_mfma_f32_16x16x32_f16(aP, bv1, oacc[1], 0, 0, 0);
            oacc[2] = __builtin_amdgcn_mfma_f32_16x16x32_f16(aP, bv2, oacc[2], 0, 0, 0);
            oacc[3] = __builtin_amdgcn_mfma_f32_16x16x32_f16(aP, bv3, oacc[3], 0, 0, 0);
        }
    }

    float inv[4];
#pragma unroll
    for (int r = 0; r < 4; ++r) {
        float s = lsum[r];
        s += __shfl_xor(s, 1);
        s += __shfl_xor(s, 2);
        s += __shfl_xor(s, 4);
        s += __shfl_xor(s, 8);
        inv[r] = 1.0f / s;
    }
#pragma unroll
    for (int r = 0; r < 4; ++r) {
        size_t rowoff = ((size_t)(b * 3136 + n0 + wid * 16 + quad * 4 + r)) * 640
                        + h * 64 + l16;
#pragma unroll
        for (int tv = 0; tv < 4; ++tv)
            cat[rowoff + tv * 16] = (_Float16)(oacc[tv][r] * inv[r]);
    }
}

// =====================================================================
extern "C" void kernel_launch(void* const* d_in, const int* in_sizes, int n_in,
                              void* d_out, int out_size, void* d_ws, size_t ws_size,
                              hipStream_t stream)
{
    const float* x           = (const float*)d_in[0];
    const float* reduce_w    = (const float*)d_in[3];
    const float* reduce_b    = (const float*)d_in[4];
    const float* reduce_g    = (const float*)d_in[5];
    const float* reduce_beta = (const float*)d_in[6];
    const float* filter_w    = (const float*)d_in[7];
    const float* filter_b    = (const float*)d_in[8];
    const float* filter_g    = (const float*)d_in[9];
    const float* filter_beta = (const float*)d_in[10];
    const float* q_w         = (const float*)d_in[11];
    const float* q_b         = (const float*)d_in[12];
    const float* ln_g        = (const float*)d_in[13];
    const float* ln_b        = (const float*)d_in[14];
    const float* kv_w        = (const float*)d_in[15];
    const float* kv_b        = (const float*)d_in[16];
    const float* kve_w       = (const float*)d_in[17];
    const float* kve_b       = (const float*)d_in[18];
    const float* proj_w      = (const float*)d_in[19];
    const float* proj_b      = (const float*)d_in[20];
    float* out = (float*)d_out;
    _Float16* hws = (_Float16*)d_ws;

    _Float16* x16    = hws + OFF_X16;
    _Float16* q16    = hws + OFF_Q16;
    _Float16* cat16  = hws + OFF_CAT;
    _Float16* r16    = hws + OFF_R16;
    _Float16* pad16  = hws + OFF_PAD;
    _Float16* dwtb16 = hws + OFF_DWTB;
    float*    kv_in  = (float*)(hws + OFF_KVIN);
    _Float16* ln16   = hws + OFF_LN16;
    _Float16* kv16   = hws + OFF_KV16;
    _Float16* wT16   = hws + OFF_WT;
    _Float16* kT16   = hws + OFF_KT;
    _Float16* qw16   = hws + OFF_QW;
    _Float16* kvw16  = hws + OFF_KVW;
    _Float16* pw16   = hws + OFF_PW;
    _Float16* rw16   = hws + OFF_RW;
    _Float16* vt16   = hws + OFF_VT;
    float*    partA  = (float*)(hws + OFF_X16);   // partials 0,1 (x16 is dead by then)
    float*    partB  = (float*)(hws + OFF_PART);  // partials 2,3

    // conversions / transposes / padding init
    cvt_f32_f16<<<dim3(6272), dim3(256), 0, stream>>>(x, x16, 1605632);
    cvt_f32_f16<<<dim3(128),  dim3(256), 0, stream>>>(q_w, qw16, 32768);
    cvt_f32_f16<<<dim3(256),  dim3(256), 0, stream>>>(kv_w, kvw16, 65536);
    cvt_f32_f16<<<dim3(160),  dim3(256), 0, stream>>>(proj_w, pw16, 40960);
    cvt_f32_f16<<<dim3(32),   dim3(256), 0, stream>>>(reduce_w, rw16, 8192);
    transpose_filter16<<<dim3(9216), dim3(256), 0, stream>>>(filter_w, wT16);
    transpose_kve16<<<dim3(4096), dim3(256), 0, stream>>>(kve_w, kT16);
    zero_half<<<dim3(1800), dim3(256), 0, stream>>>(pad16, 460800);

    // q = x @ q_w.T + q_b  -> fp16
    gemm16<0, 2><<<dim3(196, 4), dim3(256), 0, stream>>>(
        x16, qw16, q16, 25088, 512, 512, 512, q_b, nullptr, nullptr);

    // r = fp16(relu(bn(conv1x1(x))))  (25088 x 128 NHWC fp16)
    gemm16<0, 1><<<dim3(196, 1), dim3(256), 0, stream>>>(
        x16, rw16, r16, 25088, 512, 512, 128, reduce_b, reduce_g, reduce_beta);

    // DWT -> padded 30x30x512
    dwt_kernel<<<dim3(6272), dim3(128), 0, stream>>>(r16, pad16);

    // 3x3 conv split-K x4 (x16 now dead; partials 0,1 overwrite it)
    conv_splitk<<<dim3(49, 4, 4), dim3(256), 0, stream>>>(pad16, wT16, partA, partB);
    conv_epi<<<dim3(1568), dim3(256), 0, stream>>>(
        partA, partB, dwtb16, filter_b, filter_g, filter_beta);

    // IDWT -> cat cols 512..639
    idwt_kernel<<<dim3(6272), dim3(128), 0, stream>>>(dwtb16, cat16);

    // kve 2x2 s2 conv -> kv_in (fp32)
    gemm16<2, 0><<<dim3(13, 4), dim3(256), 0, stream>>>(
        dwtb16, kT16, kv_in, 1568, 2048, 0, 512, kve_b, nullptr, nullptr);

    // LayerNorm -> fp16
    ln_kernel<<<dim3(392), dim3(256), 0, stream>>>(kv_in, ln16, ln_g, ln_b);

    // kv = ln @ kv_w.T + kv_b -> fp16 (1568 x 1024)
    gemm16<0, 2><<<dim3(13, 8), dim3(256), 0, stream>>>(
        ln16, kvw16, kv16, 1568, 512, 512, 1024, kv_b, nullptr, nullptr);

    // V^T for attention B-operand
    vt_prep<<<dim3(3584), dim3(256), 0, stream>>>(kv16, vt16);

    // attention -> cat cols 0..511
    attn_mfma<<<dim3(3136), dim3(256), 0, stream>>>(q16, kv16, vt16, cat16);

    // out = cat @ proj_w.T + proj_b  (fp32)
    gemm16<0, 0><<<dim3(196, 4), dim3(256), 0, stream>>>(
        cat16, pw16, out, 25088, 640, 640, 512, proj_b, nullptr, nullptr);
}